// Round 7
// baseline (607.838 us; speedup 1.0000x reference)
//
#include <hip/hip_runtime.h>

#define N_NODES 50000
#define N_EDGES 800000
#define F_IN 24
#define HDIM 128
#define N_GRAPHS 100
#define BN_EPS 1e-5f
#define NBLK 196  // ceil(N_NODES/256)
#define ROWS_PER_GRAPH (N_NODES / N_GRAPHS)  // 500, exact by construction of `batch`

typedef _Float16 h2 __attribute__((ext_vector_type(2)));  // lowers to v_pk_* ops

// ---------------- weight prep (all 3 layers in one launch) ------------------------
// Wcat[k][0:128]=Wtop-Wbot, Wcat[k][128:256]=Wbot
__global__ void k_prep_all(const float* __restrict__ W1, const float* __restrict__ W2,
                           const float* __restrict__ W3, float* __restrict__ Wc1,
                           float* __restrict__ Wc2, float* __restrict__ Wc3) {
    int b = blockIdx.x;           // 0..(24+128+128-1)
    int j = threadIdx.x;          // 0..255
    const float* W; float* Wc; int k, Fh;
    if (b < F_IN)              { W = W1; Wc = Wc1; k = b;               Fh = F_IN; }
    else if (b < F_IN + HDIM)  { W = W2; Wc = Wc2; k = b - F_IN;        Fh = HDIM; }
    else                       { W = W3; Wc = Wc3; k = b - F_IN - HDIM; Fh = HDIM; }
    float wb = W[(k + Fh) * HDIM + (j & 127)];
    float wt = W[k * HDIM + (j & 127)];
    Wc[k * 256 + j] = (j < HDIM) ? (wt - wb) : wb;
}

// ---------------- edge sort: histogram / hierarchical scan / scatter -------------
__global__ void k_hist(const int* __restrict__ dst, unsigned* __restrict__ deg) {
    int e = blockIdx.x * 256 + threadIdx.x;
    if (e < N_EDGES) atomicAdd(&deg[dst[e]], 1u);
}

__global__ __launch_bounds__(256) void k_blocksum(const unsigned* __restrict__ deg,
                                                  unsigned* __restrict__ bsum) {
    int i = blockIdx.x * 256 + threadIdx.x;
    unsigned v = (i < N_NODES) ? deg[i] : 0u;
    __shared__ unsigned s[4];
    for (int o = 32; o > 0; o >>= 1) v += __shfl_down(v, o);
    if ((threadIdx.x & 63) == 0) s[threadIdx.x >> 6] = v;
    __syncthreads();
    if (threadIdx.x == 0) bsum[blockIdx.x] = s[0] + s[1] + s[2] + s[3];
}

__global__ __launch_bounds__(256) void k_scanb(const unsigned* __restrict__ bsum,
                                               unsigned* __restrict__ bbase) {
    __shared__ unsigned s[256];
    int t = threadIdx.x;
    unsigned v = (t < NBLK) ? bsum[t] : 0u;
    s[t] = v;
    __syncthreads();
    for (int d = 1; d < 256; d <<= 1) {
        unsigned u = (t >= d) ? s[t - d] : 0u;
        __syncthreads();
        s[t] += u;
        __syncthreads();
    }
    if (t < NBLK) bbase[t] = s[t] - v;  // exclusive
}

__global__ __launch_bounds__(256) void k_offsets(const unsigned* __restrict__ deg,
                                                 const unsigned* __restrict__ bbase,
                                                 unsigned* __restrict__ off,
                                                 unsigned* __restrict__ cur) {
    __shared__ unsigned s[256];
    int t = threadIdx.x;
    int i = blockIdx.x * 256 + t;
    unsigned v = (i < N_NODES) ? deg[i] : 0u;
    s[t] = v;
    __syncthreads();
    for (int d = 1; d < 256; d <<= 1) {
        unsigned u = (t >= d) ? s[t - d] : 0u;
        __syncthreads();
        s[t] += u;
        __syncthreads();
    }
    if (i < N_NODES) {
        unsigned o = bbase[blockIdx.x] + s[t] - v;
        off[i] = o;
        cur[i] = o;
    }
}

__global__ void k_scatter(const int* __restrict__ src, const int* __restrict__ dst,
                          unsigned* __restrict__ cur, unsigned* __restrict__ ssrc) {
    int e = blockIdx.x * 256 + threadIdx.x;
    if (e < N_EDGES) {
        unsigned p = atomicAdd(&cur[dst[e]], 1u);
        ssrc[p] = (unsigned)src[e];
    }
}

// ---------------- node matmul: A(fp32) = bn(X)@(Wt-Wb)+b (y=0), C(fp16) = bn(X)@Wb (y=1)
// block: 256 threads; 128 rows x 128 cols; thread tile 8x8 (cols cg*4..+3 and 64+cg*4..+3).
// Per kk: 4 LDS b128 (all 2-way/broadcast = conflict-free) feeding 64 FMA -> VALU-bound.
template <int K, int KC, bool BN>
__global__ __launch_bounds__(256) void k_mm(const float* __restrict__ X,
                                            const float* __restrict__ Wcat,
                                            const float* __restrict__ bias,
                                            const float* __restrict__ scale,
                                            const float* __restrict__ shift,
                                            float* __restrict__ A, _Float16* __restrict__ C) {
    __shared__ float Xs[KC * 132];   // [kk][row 0..127], pad 128->132
    __shared__ float Ws[KC * 128];   // [kk][col]
    int tid = threadIdx.x;
    int row0 = blockIdx.x * 128;
    const bool isA = (blockIdx.y == 0);
    const int colbase = isA ? 0 : 128;
    int cg = tid & 15;        // col group
    int rg = tid >> 4;        // row group: rows rg*8..rg*8+7

    float acc[8][8];
#pragma unroll
    for (int ri = 0; ri < 8; ++ri)
#pragma unroll
        for (int ci = 0; ci < 4; ++ci) {
            acc[ri][ci]     = isA ? bias[cg * 4 + ci]      : 0.f;
            acc[ri][ci + 4] = isA ? bias[64 + cg * 4 + ci] : 0.f;
        }

    for (int k0 = 0; k0 < K; k0 += KC) {
        __syncthreads();
        // stage X chunk (transposed): Xs[c][r] = bn(X[row0+r][k0+c])
        {
            const int C4 = KC / 4;
            for (int i = tid; i < 128 * C4; i += 256) {
                int c4 = i % C4, r = i / C4;
                int row = row0 + r;
                float4 v = make_float4(0.f, 0.f, 0.f, 0.f);
                if (row < N_NODES) v = *(const float4*)&X[row * K + k0 + c4 * 4];
                if (BN) {
                    int c = k0 + c4 * 4;
                    v.x = fmaxf(v.x * scale[c + 0] + shift[c + 0], 0.f);
                    v.y = fmaxf(v.y * scale[c + 1] + shift[c + 1], 0.f);
                    v.z = fmaxf(v.z * scale[c + 2] + shift[c + 2], 0.f);
                    v.w = fmaxf(v.w * scale[c + 3] + shift[c + 3], 0.f);
                }
                Xs[(c4 * 4 + 0) * 132 + r] = v.x;
                Xs[(c4 * 4 + 1) * 132 + r] = v.y;
                Xs[(c4 * 4 + 2) * 132 + r] = v.z;
                Xs[(c4 * 4 + 3) * 132 + r] = v.w;
            }
        }
        // stage W chunk: Ws[kr][col] = Wcat[k0+kr][colbase+col]
        for (int i = tid; i < KC * 32; i += 256) {
            int c4 = i & 31, kr = i >> 5;
            *(float4*)&Ws[kr * 128 + c4 * 4] =
                *(const float4*)&Wcat[(k0 + kr) * 256 + colbase + c4 * 4];
        }
        __syncthreads();
#pragma unroll
        for (int kk = 0; kk < KC; ++kk) {
            float4 x0 = *(const float4*)&Xs[kk * 132 + rg * 8];
            float4 x1 = *(const float4*)&Xs[kk * 132 + rg * 8 + 4];
            float4 w0 = *(const float4*)&Ws[kk * 128 + cg * 4];
            float4 w1 = *(const float4*)&Ws[kk * 128 + 64 + cg * 4];
            float xv[8] = {x0.x, x0.y, x0.z, x0.w, x1.x, x1.y, x1.z, x1.w};
            float wv[8] = {w0.x, w0.y, w0.z, w0.w, w1.x, w1.y, w1.z, w1.w};
#pragma unroll
            for (int ri = 0; ri < 8; ++ri)
#pragma unroll
                for (int ci = 0; ci < 8; ++ci)
                    acc[ri][ci] += xv[ri] * wv[ci];
        }
    }

#pragma unroll
    for (int ri = 0; ri < 8; ++ri) {
        int row = row0 + rg * 8 + ri;
        if (row < N_NODES) {
            if (isA) {
                *(float4*)&A[row * HDIM + cg * 4] =
                    make_float4(acc[ri][0], acc[ri][1], acc[ri][2], acc[ri][3]);
                *(float4*)&A[row * HDIM + 64 + cg * 4] =
                    make_float4(acc[ri][4], acc[ri][5], acc[ri][6], acc[ri][7]);
            } else {
                union { h2 h[2]; uint2 u; } p0, p1;
                p0.h[0] = h2{(_Float16)acc[ri][0], (_Float16)acc[ri][1]};
                p0.h[1] = h2{(_Float16)acc[ri][2], (_Float16)acc[ri][3]};
                p1.h[0] = h2{(_Float16)acc[ri][4], (_Float16)acc[ri][5]};
                p1.h[1] = h2{(_Float16)acc[ri][6], (_Float16)acc[ri][7]};
                *(uint2*)&C[row * HDIM + cg * 4] = p0.u;
                *(uint2*)&C[row * HDIM + 64 + cg * 4] = p1.u;
            }
        }
    }
}

// ---------------- aggregation: h[i][2l..2l+1] = relu(A + max_e C_fp16[src]) ------
// 1 wave per node (64 lanes x 2 ch as packed fp16), 4 nodes/block, 8-deep unroll.
__global__ __launch_bounds__(256) void k_agg(const float* __restrict__ A,
                                             const h2* __restrict__ Cc,   // 64 h2/row
                                             const unsigned* __restrict__ off,
                                             const unsigned* __restrict__ deg,
                                             const unsigned* __restrict__ ssrc,
                                             float* __restrict__ H) {
    __shared__ unsigned sl[4][64];
    int w = threadIdx.x >> 6;       // wave id 0..3
    int lane = threadIdx.x & 63;
    int i = blockIdx.x * 4 + w;     // node (N_NODES divisible by 4)
    int d = (int)deg[i];
    unsigned o = off[i];
    union { unsigned short us[2]; h2 v; } ninf;
    ninf.us[0] = 0xFC00; ninf.us[1] = 0xFC00;  // -inf, -inf
    h2 m2 = ninf.v;
    for (int base = 0; base < d; base += 64) {
        int cntc = min(64, d - base);
        if (lane < cntc) sl[w][lane] = ssrc[o + base + lane];
        // same-wave LDS producer/consumer: compiler inserts lgkmcnt wait, no barrier
        int e = 0;
        for (; e + 8 <= cntc; e += 8) {
            unsigned s0 = sl[w][e + 0], s1 = sl[w][e + 1], s2 = sl[w][e + 2], s3 = sl[w][e + 3];
            unsigned s4 = sl[w][e + 4], s5 = sl[w][e + 5], s6 = sl[w][e + 6], s7 = sl[w][e + 7];
            h2 v0 = Cc[s0 * 64 + lane];
            h2 v1 = Cc[s1 * 64 + lane];
            h2 v2 = Cc[s2 * 64 + lane];
            h2 v3 = Cc[s3 * 64 + lane];
            h2 v4 = Cc[s4 * 64 + lane];
            h2 v5 = Cc[s5 * 64 + lane];
            h2 v6 = Cc[s6 * 64 + lane];
            h2 v7 = Cc[s7 * 64 + lane];
            h2 a0 = __builtin_elementwise_max(v0, v1);
            h2 a1 = __builtin_elementwise_max(v2, v3);
            h2 a2 = __builtin_elementwise_max(v4, v5);
            h2 a3 = __builtin_elementwise_max(v6, v7);
            h2 b0 = __builtin_elementwise_max(a0, a1);
            h2 b1 = __builtin_elementwise_max(a2, a3);
            m2 = __builtin_elementwise_max(m2, __builtin_elementwise_max(b0, b1));
        }
        if (e + 4 <= cntc) {
            unsigned s0 = sl[w][e + 0], s1 = sl[w][e + 1], s2 = sl[w][e + 2], s3 = sl[w][e + 3];
            h2 v0 = Cc[s0 * 64 + lane];
            h2 v1 = Cc[s1 * 64 + lane];
            h2 v2 = Cc[s2 * 64 + lane];
            h2 v3 = Cc[s3 * 64 + lane];
            h2 a0 = __builtin_elementwise_max(v0, v1);
            h2 a1 = __builtin_elementwise_max(v2, v3);
            m2 = __builtin_elementwise_max(m2, __builtin_elementwise_max(a0, a1));
            e += 4;
        }
        for (; e < cntc; ++e)
            m2 = __builtin_elementwise_max(m2, Cc[sl[w][e] * 64 + lane]);
    }
    float2 a = *(const float2*)&A[i * HDIM + lane * 2];
    float2 hv;
    hv.x = (d > 0) ? fmaxf(a.x + (float)m2.x, 0.f) : 0.f;
    hv.y = (d > 0) ? fmaxf(a.y + (float)m2.y, 0.f) : 0.f;
    *(float2*)&H[i * HDIM + lane * 2] = hv;
}

// ---------------- BN stats --------------------------------------------------------
__global__ __launch_bounds__(128) void k_stats(const float* __restrict__ H,
                                               float* __restrict__ sums) {
    int k = threadIdx.x;
    int b = blockIdx.x;          // 1000 blocks x 50 rows
    int lo = b * 50, hi = min(N_NODES, lo + 50);
    float s = 0.f, s2 = 0.f;
    for (int r = lo; r < hi; ++r) {
        float v = H[r * HDIM + k];
        s += v; s2 += v * v;
    }
    atomicAdd(&sums[k], s);
    atomicAdd(&sums[HDIM + k], s2);
}

__global__ void k_finstats(const float* __restrict__ sums, const float* __restrict__ g,
                           const float* __restrict__ be, float* __restrict__ scale,
                           float* __restrict__ shift) {
    int k = threadIdx.x;  // 128
    float mean = sums[k] / (float)N_NODES;
    float var = sums[HDIM + k] / (float)N_NODES - mean * mean;
    var = fmaxf(var, 0.f);
    float sc = g[k] / sqrtf(var + BN_EPS);
    scale[k] = sc;
    shift[k] = be[k] - mean * sc;
}

// ---------------- fused mean-pool + BN3-affine + linear + relu -------------------
// One block per graph; rows [g*500, (g+1)*500) exactly (batch = arange // 500).
__global__ __launch_bounds__(128) void k_poolout(const float* __restrict__ H,
                                                 const float* __restrict__ sc,
                                                 const float* __restrict__ sh,
                                                 const float* __restrict__ Wl,
                                                 const float* __restrict__ bl,
                                                 float* __restrict__ out) {
    int g = blockIdx.x;
    int k = threadIdx.x;  // 128
    const float* base = H + (size_t)g * ROWS_PER_GRAPH * HDIM;
    float s = 0.f;
#pragma unroll 4
    for (int r = 0; r < ROWS_PER_GRAPH; ++r) s += base[r * HDIM + k];
    float pb = sc[k] * (s * (1.f / (float)ROWS_PER_GRAPH)) + sh[k];
    float p = pb * Wl[k];
    __shared__ float red[2];
    for (int o = 32; o > 0; o >>= 1) p += __shfl_down(p, o);
    if ((k & 63) == 0) red[k >> 6] = p;
    __syncthreads();
    if (k == 0) out[g] = fmaxf(red[0] + red[1] + bl[0], 0.f);
}

// ---------------- launcher --------------------------------------------------------
extern "C" void kernel_launch(void* const* d_in, const int* in_sizes, int n_in,
                              void* d_out, int out_size, void* d_ws, size_t ws_size,
                              hipStream_t stream) {
    const float* x   = (const float*)d_in[0];
    const int* ei    = (const int*)d_in[1];
    const float* W1  = (const float*)d_in[3];
    const float* b1  = (const float*)d_in[4];
    const float* W2  = (const float*)d_in[5];
    const float* b2  = (const float*)d_in[6];
    const float* W3  = (const float*)d_in[7];
    const float* b3  = (const float*)d_in[8];
    const float* g1  = (const float*)d_in[9];
    const float* be1 = (const float*)d_in[10];
    const float* g2  = (const float*)d_in[11];
    const float* be2 = (const float*)d_in[12];
    const float* g3  = (const float*)d_in[13];
    const float* be3 = (const float*)d_in[14];
    const float* Wl  = (const float*)d_in[15];
    const float* bl  = (const float*)d_in[16];
    float* out = (float*)d_out;

    const int* srcp = ei;
    const int* dstp = ei + N_EDGES;

    // ---- workspace carve-up (256B aligned) ----
    char* ws = (char*)d_ws;
    size_t o = 0;
    auto alloc = [&](size_t bytes) -> void* {
        o = (o + 255) & ~(size_t)255;
        void* p = ws + o;
        o += bytes;
        return p;
    };
    float* A      = (float*)alloc((size_t)N_NODES * HDIM * 4);
    _Float16* C   = (_Float16*)alloc((size_t)N_NODES * HDIM * 2);
    float* h      = (float*)alloc((size_t)N_NODES * HDIM * 4);
    float* Wcat1  = (float*)alloc((size_t)F_IN * 256 * 4);
    float* Wcat2  = (float*)alloc((size_t)HDIM * 256 * 4);
    float* Wcat3  = (float*)alloc((size_t)HDIM * 256 * 4);
    unsigned* deg  = (unsigned*)alloc((size_t)N_NODES * 4);
    unsigned* off  = (unsigned*)alloc((size_t)N_NODES * 4);
    unsigned* cur  = (unsigned*)alloc((size_t)N_NODES * 4);
    unsigned* ssrc = (unsigned*)alloc((size_t)N_EDGES * 4);
    unsigned* bsum = (unsigned*)alloc((size_t)NBLK * 4);
    unsigned* bbase= (unsigned*)alloc((size_t)NBLK * 4);
    float* sums    = (float*)alloc(3 * 256 * 4);     // [layer][sum|sumsq]
    float* scbuf   = (float*)alloc(6 * 128 * 4);     // sc1,sh1,sc2,sh2,sc3,sh3
    (void)ws_size; (void)n_in; (void)in_sizes; (void)out_size;

    float* sums0 = sums;        float* sums1 = sums + 256;  float* sums2 = sums + 512;
    float* sc1 = scbuf;         float* sh1 = scbuf + 128;
    float* sc2 = scbuf + 256;   float* sh2 = scbuf + 384;
    float* sc3 = scbuf + 512;   float* sh3 = scbuf + 640;

    // one memset covers deg..sums; off/cur/ssrc/bsum/bbase are fully overwritten
    // before use, so zeroing them is harmless.
    size_t zlen = (size_t)((char*)(sums + 768) - (char*)deg);
    (void)hipMemsetAsync(deg, 0, zlen, stream);

    // weight prep + edge sort
    k_prep_all<<<F_IN + 2 * HDIM, 256, 0, stream>>>(W1, W2, W3, Wcat1, Wcat2, Wcat3);
    k_hist<<<(N_EDGES + 255) / 256, 256, 0, stream>>>(dstp, deg);
    k_blocksum<<<NBLK, 256, 0, stream>>>(deg, bsum);
    k_scanb<<<1, 256, 0, stream>>>(bsum, bbase);
    k_offsets<<<NBLK, 256, 0, stream>>>(deg, bbase, off, cur);
    k_scatter<<<(N_EDGES + 255) / 256, 256, 0, stream>>>(srcp, dstp, cur, ssrc);

    const dim3 MMG((N_NODES + 127) / 128, 2);  // 391 x 2
    const int AGB = N_NODES / 4;               // 12500 blocks, 4 nodes each

    // layer 1
    k_mm<F_IN, F_IN, false><<<MMG, 256, 0, stream>>>(x, Wcat1, b1, nullptr, nullptr, A, C);
    k_agg<<<AGB, 256, 0, stream>>>(A, (const h2*)C, off, deg, ssrc, h);
    k_stats<<<1000, 128, 0, stream>>>(h, sums0);
    k_finstats<<<1, 128, 0, stream>>>(sums0, g1, be1, sc1, sh1);

    // layer 2
    k_mm<HDIM, 32, true><<<MMG, 256, 0, stream>>>(h, Wcat2, b2, sc1, sh1, A, C);
    k_agg<<<AGB, 256, 0, stream>>>(A, (const h2*)C, off, deg, ssrc, h);
    k_stats<<<1000, 128, 0, stream>>>(h, sums1);
    k_finstats<<<1, 128, 0, stream>>>(sums1, g2, be2, sc2, sh2);

    // layer 3
    k_mm<HDIM, 32, true><<<MMG, 256, 0, stream>>>(h, Wcat3, b3, sc2, sh2, A, C);
    k_agg<<<AGB, 256, 0, stream>>>(A, (const h2*)C, off, deg, ssrc, h);
    k_stats<<<1000, 128, 0, stream>>>(h, sums2);
    k_finstats<<<1, 128, 0, stream>>>(sums2, g3, be3, sc3, sh3);

    // fused pool + BN3 + linear + relu
    k_poolout<<<N_GRAPHS, 128, 0, stream>>>(h, sc3, sh3, Wl, bl, out);
}

// Round 8
// 586.242 us; speedup vs baseline: 1.0368x; 1.0368x over previous
//
#include <hip/hip_runtime.h>

#define N_NODES 50000
#define N_EDGES 800000
#define F_IN 24
#define HDIM 128
#define N_GRAPHS 100
#define BN_EPS 1e-5f
#define NBLK 196                          // ceil(N_NODES/256)
#define ROWS_PER_GRAPH (N_NODES / N_GRAPHS)
#define MM_GRID 782                       // ceil(N_NODES/64), 64-row tiles
#define HIST_BLKS ((N_EDGES + 255) / 256) // 3125
#define PREP_BLKS (F_IN + 2 * HDIM)       // 280

typedef _Float16 h2 __attribute__((ext_vector_type(2)));  // lowers to v_pk_* ops

// ---------------- node matmul body (R6-verified shape: 64 rows x 128 cols, 8x4 tile)
// A(fp32) = bn(X)@(Wt-Wb)+b when isA; C(fp16) = bn(X)@Wb otherwise. K-chunked, all LDS.
template <int K, int KC, bool BN>
__device__ void mm_body(int bx, bool isA, const float* __restrict__ X,
                        const float* __restrict__ Wcat, const float* __restrict__ bias,
                        const float* __restrict__ scale, const float* __restrict__ shift,
                        float* __restrict__ A, _Float16* __restrict__ C) {
    __shared__ float Xs[KC * 68];    // [kk][row], pad 64->68
    __shared__ float Ws[KC * 128];   // [kk][col]
    int tid = threadIdx.x;
    int row0 = bx * 64;
    const int colbase = isA ? 0 : 128;
    int cg = tid & 31;        // col group: cols cg*4..cg*4+3
    int rg = tid >> 5;        // row group: rows rg*8..rg*8+7

    float acc[8][4];
#pragma unroll
    for (int ri = 0; ri < 8; ++ri)
#pragma unroll
        for (int ci = 0; ci < 4; ++ci)
            acc[ri][ci] = isA ? bias[cg * 4 + ci] : 0.f;

    for (int k0 = 0; k0 < K; k0 += KC) {
        __syncthreads();
        {
            const int C4 = KC / 4;
            for (int i = tid; i < 64 * C4; i += 256) {
                int c4 = i % C4, r = i / C4;
                int row = row0 + r;
                float4 v = make_float4(0.f, 0.f, 0.f, 0.f);
                if (row < N_NODES) v = *(const float4*)&X[row * K + k0 + c4 * 4];
                if (BN) {
                    int c = k0 + c4 * 4;
                    v.x = fmaxf(v.x * scale[c + 0] + shift[c + 0], 0.f);
                    v.y = fmaxf(v.y * scale[c + 1] + shift[c + 1], 0.f);
                    v.z = fmaxf(v.z * scale[c + 2] + shift[c + 2], 0.f);
                    v.w = fmaxf(v.w * scale[c + 3] + shift[c + 3], 0.f);
                }
                Xs[(c4 * 4 + 0) * 68 + r] = v.x;
                Xs[(c4 * 4 + 1) * 68 + r] = v.y;
                Xs[(c4 * 4 + 2) * 68 + r] = v.z;
                Xs[(c4 * 4 + 3) * 68 + r] = v.w;
            }
        }
        for (int i = tid; i < KC * 32; i += 256) {
            int c4 = i & 31, kr = i >> 5;
            *(float4*)&Ws[kr * 128 + c4 * 4] =
                *(const float4*)&Wcat[(k0 + kr) * 256 + colbase + c4 * 4];
        }
        __syncthreads();
#pragma unroll
        for (int kk = 0; kk < KC; ++kk) {
            float4 t0 = *(const float4*)&Xs[kk * 68 + rg * 8];
            float4 t1 = *(const float4*)&Xs[kk * 68 + rg * 8 + 4];
            float4 w = *(const float4*)&Ws[kk * 128 + cg * 4];
            float t[8] = {t0.x, t0.y, t0.z, t0.w, t1.x, t1.y, t1.z, t1.w};
            float wv[4] = {w.x, w.y, w.z, w.w};
#pragma unroll
            for (int ri = 0; ri < 8; ++ri)
#pragma unroll
                for (int ci = 0; ci < 4; ++ci)
                    acc[ri][ci] += t[ri] * wv[ci];
        }
    }

#pragma unroll
    for (int ri = 0; ri < 8; ++ri) {
        int row = row0 + rg * 8 + ri;
        if (row < N_NODES) {
            if (isA) {
                *(float4*)&A[row * HDIM + cg * 4] =
                    make_float4(acc[ri][0], acc[ri][1], acc[ri][2], acc[ri][3]);
            } else {
                union { h2 h[2]; uint2 u; } pk;
                pk.h[0] = h2{(_Float16)acc[ri][0], (_Float16)acc[ri][1]};
                pk.h[1] = h2{(_Float16)acc[ri][2], (_Float16)acc[ri][3]};
                *(uint2*)&C[row * HDIM + cg * 4] = pk.u;
            }
        }
    }
}

template <int K, int KC, bool BN>
__global__ __launch_bounds__(256) void k_mm(const float* __restrict__ X,
                                            const float* __restrict__ Wcat,
                                            const float* __restrict__ bias,
                                            const float* __restrict__ scale,
                                            const float* __restrict__ shift,
                                            float* __restrict__ A, _Float16* __restrict__ C) {
    mm_body<K, KC, BN>(blockIdx.x, blockIdx.y == 0, X, Wcat, bias, scale, shift, A, C);
}

// ---------------- fused: weight prep (280 blocks) + degree histogram (3125 blocks)
__global__ void k_pre(const float* __restrict__ W1, const float* __restrict__ W2,
                      const float* __restrict__ W3, float* __restrict__ Wc1,
                      float* __restrict__ Wc2, float* __restrict__ Wc3,
                      const int* __restrict__ dst, unsigned* __restrict__ deg) {
    int b = blockIdx.x;
    int j = threadIdx.x;
    if (b < PREP_BLKS) {
        const float* W; float* Wc; int k, Fh;
        if (b < F_IN)             { W = W1; Wc = Wc1; k = b;               Fh = F_IN; }
        else if (b < F_IN + HDIM) { W = W2; Wc = Wc2; k = b - F_IN;        Fh = HDIM; }
        else                      { W = W3; Wc = Wc3; k = b - F_IN - HDIM; Fh = HDIM; }
        float wb = W[(k + Fh) * HDIM + (j & 127)];
        float wt = W[k * HDIM + (j & 127)];
        Wc[k * 256 + j] = (j < HDIM) ? (wt - wb) : wb;
    } else {
        int e = (b - PREP_BLKS) * 256 + j;
        if (e < N_EDGES) atomicAdd(&deg[dst[e]], 1u);
    }
}

// ---------------- single-kernel scan: local scan -> publish(+1 bias) -> spin -> offsets
// 196 blocks <= CU count => all co-resident; device-scope atomics for cross-XCD safety.
__global__ __launch_bounds__(256) void k_scanall(const unsigned* __restrict__ deg,
                                                 unsigned* __restrict__ bsum,  // zeroed
                                                 unsigned* __restrict__ off,
                                                 unsigned* __restrict__ cur) {
    __shared__ unsigned s[256];
    int t = threadIdx.x;
    int b = blockIdx.x;
    int i = b * 256 + t;
    unsigned v = (i < N_NODES) ? deg[i] : 0u;
    s[t] = v;
    __syncthreads();
    for (int d = 1; d < 256; d <<= 1) {
        unsigned u = (t >= d) ? s[t - d] : 0u;
        __syncthreads();
        s[t] += u;
        __syncthreads();
    }
    unsigned locex = s[t] - v;           // in-block exclusive prefix
    if (t == 255) atomicExch(&bsum[b], s[255] + 1u);   // publish total, +1 = ready flag
    __syncthreads();                     // everyone done with s before reuse
    unsigned bs = 0;
    if (t < NBLK) {
        unsigned x;
        do { x = atomicAdd(&bsum[t], 0u); } while (x == 0u);
        bs = x - 1u;
    }
    s[t] = (t < NBLK) ? bs : 0u;
    __syncthreads();
    for (int d = 1; d < 256; d <<= 1) {
        unsigned u = (t >= d) ? s[t - d] : 0u;
        __syncthreads();
        s[t] += u;
        __syncthreads();
    }
    unsigned bexcl = (b == 0) ? 0u : s[b - 1];
    if (i < N_NODES) {
        unsigned o = bexcl + locex;
        off[i] = o;
        cur[i] = o;
    }
}

// ---------------- fused: layer-1 matmul (1564 blocks) + edge scatter (3125 blocks)
__global__ __launch_bounds__(256) void k_l1(const float* __restrict__ x,
                                            const float* __restrict__ Wcat1,
                                            const float* __restrict__ b1,
                                            float* __restrict__ A, _Float16* __restrict__ C,
                                            const int* __restrict__ src,
                                            const int* __restrict__ dst,
                                            unsigned* __restrict__ cur,
                                            unsigned* __restrict__ ssrc) {
    int b = blockIdx.x;
    if (b < 2 * MM_GRID) {
        mm_body<F_IN, F_IN, false>(b >> 1, (b & 1) == 0, x, Wcat1, b1, nullptr, nullptr, A, C);
    } else {
        int e = (b - 2 * MM_GRID) * 256 + threadIdx.x;
        if (e < N_EDGES) {
            unsigned p = atomicAdd(&cur[dst[e]], 1u);
            ssrc[p] = (unsigned)src[e];
        }
    }
}

// ---------------- aggregation: h[i][2l..2l+1] = relu(A + max_e C_fp16[src]) ------
__global__ __launch_bounds__(256) void k_agg(const float* __restrict__ A,
                                             const h2* __restrict__ Cc,   // 64 h2/row
                                             const unsigned* __restrict__ off,
                                             const unsigned* __restrict__ deg,
                                             const unsigned* __restrict__ ssrc,
                                             float* __restrict__ H) {
    __shared__ unsigned sl[4][64];
    int w = threadIdx.x >> 6;
    int lane = threadIdx.x & 63;
    int i = blockIdx.x * 4 + w;
    int d = (int)deg[i];
    unsigned o = off[i];
    union { unsigned short us[2]; h2 v; } ninf;
    ninf.us[0] = 0xFC00; ninf.us[1] = 0xFC00;
    h2 m2 = ninf.v;
    for (int base = 0; base < d; base += 64) {
        int cntc = min(64, d - base);
        if (lane < cntc) sl[w][lane] = ssrc[o + base + lane];
        int e = 0;
        for (; e + 8 <= cntc; e += 8) {
            unsigned s0 = sl[w][e + 0], s1 = sl[w][e + 1], s2 = sl[w][e + 2], s3 = sl[w][e + 3];
            unsigned s4 = sl[w][e + 4], s5 = sl[w][e + 5], s6 = sl[w][e + 6], s7 = sl[w][e + 7];
            h2 v0 = Cc[s0 * 64 + lane];
            h2 v1 = Cc[s1 * 64 + lane];
            h2 v2 = Cc[s2 * 64 + lane];
            h2 v3 = Cc[s3 * 64 + lane];
            h2 v4 = Cc[s4 * 64 + lane];
            h2 v5 = Cc[s5 * 64 + lane];
            h2 v6 = Cc[s6 * 64 + lane];
            h2 v7 = Cc[s7 * 64 + lane];
            h2 a0 = __builtin_elementwise_max(v0, v1);
            h2 a1 = __builtin_elementwise_max(v2, v3);
            h2 a2 = __builtin_elementwise_max(v4, v5);
            h2 a3 = __builtin_elementwise_max(v6, v7);
            h2 b0 = __builtin_elementwise_max(a0, a1);
            h2 b1 = __builtin_elementwise_max(a2, a3);
            m2 = __builtin_elementwise_max(m2, __builtin_elementwise_max(b0, b1));
        }
        if (e + 4 <= cntc) {
            unsigned s0 = sl[w][e + 0], s1 = sl[w][e + 1], s2 = sl[w][e + 2], s3 = sl[w][e + 3];
            h2 v0 = Cc[s0 * 64 + lane];
            h2 v1 = Cc[s1 * 64 + lane];
            h2 v2 = Cc[s2 * 64 + lane];
            h2 v3 = Cc[s3 * 64 + lane];
            h2 a0 = __builtin_elementwise_max(v0, v1);
            h2 a1 = __builtin_elementwise_max(v2, v3);
            m2 = __builtin_elementwise_max(m2, __builtin_elementwise_max(a0, a1));
            e += 4;
        }
        for (; e < cntc; ++e)
            m2 = __builtin_elementwise_max(m2, Cc[sl[w][e] * 64 + lane]);
    }
    float2 a = *(const float2*)&A[i * HDIM + lane * 2];
    float2 hv;
    hv.x = (d > 0) ? fmaxf(a.x + (float)m2.x, 0.f) : 0.f;
    hv.y = (d > 0) ? fmaxf(a.y + (float)m2.y, 0.f) : 0.f;
    *(float2*)&H[i * HDIM + lane * 2] = hv;
}

// ---------------- BN stats + last-block finstats ---------------------------------
__global__ __launch_bounds__(128) void k_statsf(const float* __restrict__ H,
                                                float* __restrict__ sums,   // zeroed
                                                const float* __restrict__ g,
                                                const float* __restrict__ be,
                                                float* __restrict__ sc, float* __restrict__ sh,
                                                unsigned* __restrict__ done) {  // zeroed
    int k = threadIdx.x;
    int b = blockIdx.x;          // 1000 blocks x 50 rows
    int lo = b * 50;
    float s = 0.f, s2 = 0.f;
    for (int r = lo; r < lo + 50; ++r) {
        float v = H[r * HDIM + k];
        s += v; s2 += v * v;
    }
    atomicAdd(&sums[k], s);
    atomicAdd(&sums[HDIM + k], s2);
    __threadfence();
    __syncthreads();
    __shared__ bool last;
    if (k == 0) last = (atomicAdd(done, 1u) == 999u);
    __syncthreads();
    if (last) {
        float S  = atomicAdd(&sums[k], 0.f);
        float S2 = atomicAdd(&sums[HDIM + k], 0.f);
        float mean = S / (float)N_NODES;
        float var = fmaxf(S2 / (float)N_NODES - mean * mean, 0.f);
        float scv = g[k] / sqrtf(var + BN_EPS);
        sc[k] = scv;
        sh[k] = be[k] - mean * scv;   // plain write: consumed by a later dispatch
    }
}

// ---------------- fused mean-pool + BN3-affine + linear + relu -------------------
__global__ __launch_bounds__(128) void k_poolout(const float* __restrict__ H,
                                                 const float* __restrict__ sc,
                                                 const float* __restrict__ sh,
                                                 const float* __restrict__ Wl,
                                                 const float* __restrict__ bl,
                                                 float* __restrict__ out) {
    int g = blockIdx.x;
    int k = threadIdx.x;
    const float* base = H + (size_t)g * ROWS_PER_GRAPH * HDIM;
    float s = 0.f;
#pragma unroll 4
    for (int r = 0; r < ROWS_PER_GRAPH; ++r) s += base[r * HDIM + k];
    float pb = sc[k] * (s * (1.f / (float)ROWS_PER_GRAPH)) + sh[k];
    float p = pb * Wl[k];
    __shared__ float red[2];
    for (int o = 32; o > 0; o >>= 1) p += __shfl_down(p, o);
    if ((k & 63) == 0) red[k >> 6] = p;
    __syncthreads();
    if (k == 0) out[g] = fmaxf(red[0] + red[1] + bl[0], 0.f);
}

// ---------------- launcher --------------------------------------------------------
extern "C" void kernel_launch(void* const* d_in, const int* in_sizes, int n_in,
                              void* d_out, int out_size, void* d_ws, size_t ws_size,
                              hipStream_t stream) {
    const float* x   = (const float*)d_in[0];
    const int* ei    = (const int*)d_in[1];
    const float* W1  = (const float*)d_in[3];
    const float* b1  = (const float*)d_in[4];
    const float* W2  = (const float*)d_in[5];
    const float* b2  = (const float*)d_in[6];
    const float* W3  = (const float*)d_in[7];
    const float* b3  = (const float*)d_in[8];
    const float* g1  = (const float*)d_in[9];
    const float* be1 = (const float*)d_in[10];
    const float* g2  = (const float*)d_in[11];
    const float* be2 = (const float*)d_in[12];
    const float* g3  = (const float*)d_in[13];
    const float* be3 = (const float*)d_in[14];
    const float* Wl  = (const float*)d_in[15];
    const float* bl  = (const float*)d_in[16];
    float* out = (float*)d_out;

    const int* srcp = ei;
    const int* dstp = ei + N_EDGES;

    // ---- workspace carve-up (256B aligned) ----
    char* ws = (char*)d_ws;
    size_t o = 0;
    auto alloc = [&](size_t bytes) -> void* {
        o = (o + 255) & ~(size_t)255;
        void* p = ws + o;
        o += bytes;
        return p;
    };
    float* A      = (float*)alloc((size_t)N_NODES * HDIM * 4);
    _Float16* C   = (_Float16*)alloc((size_t)N_NODES * HDIM * 2);
    float* h      = (float*)alloc((size_t)N_NODES * HDIM * 4);
    float* Wcat1  = (float*)alloc((size_t)F_IN * 256 * 4);
    float* Wcat2  = (float*)alloc((size_t)HDIM * 256 * 4);
    float* Wcat3  = (float*)alloc((size_t)HDIM * 256 * 4);
    // ---- zeroed region: deg .. done (single memset) ----
    unsigned* deg  = (unsigned*)alloc((size_t)N_NODES * 4);
    unsigned* bsum = (unsigned*)alloc((size_t)NBLK * 4);
    float* sums    = (float*)alloc(3 * 256 * 4);     // [layer][sum|sumsq]
    unsigned* done = (unsigned*)alloc(8 * 4);
    // ---- not zeroed (fully overwritten) ----
    unsigned* off  = (unsigned*)alloc((size_t)N_NODES * 4);
    unsigned* cur  = (unsigned*)alloc((size_t)N_NODES * 4);
    unsigned* ssrc = (unsigned*)alloc((size_t)N_EDGES * 4);
    float* scbuf   = (float*)alloc(6 * 128 * 4);     // sc1,sh1,sc2,sh2,sc3,sh3
    (void)ws_size; (void)n_in; (void)in_sizes; (void)out_size;

    float* sums0 = sums;        float* sums1 = sums + 256;  float* sums2 = sums + 512;
    float* sc1 = scbuf;         float* sh1 = scbuf + 128;
    float* sc2 = scbuf + 256;   float* sh2 = scbuf + 384;
    float* sc3 = scbuf + 512;   float* sh3 = scbuf + 640;

    size_t zlen = (size_t)((char*)(done + 8) - (char*)deg);
    (void)hipMemsetAsync(deg, 0, zlen, stream);                       // 1

    k_pre<<<PREP_BLKS + HIST_BLKS, 256, 0, stream>>>(W1, W2, W3, Wcat1, Wcat2, Wcat3,
                                                     dstp, deg);      // 2
    k_scanall<<<NBLK, 256, 0, stream>>>(deg, bsum, off, cur);         // 3

    const dim3 MMG(MM_GRID, 2);
    const int AGB = N_NODES / 4;

    // layer 1 (mm fused with scatter)
    k_l1<<<2 * MM_GRID + HIST_BLKS, 256, 0, stream>>>(x, Wcat1, b1, A, C,
                                                      srcp, dstp, cur, ssrc);  // 4
    k_agg<<<AGB, 256, 0, stream>>>(A, (const h2*)C, off, deg, ssrc, h);        // 5
    k_statsf<<<1000, 128, 0, stream>>>(h, sums0, g1, be1, sc1, sh1, done + 0); // 6

    // layer 2
    k_mm<HDIM, 32, true><<<MMG, 256, 0, stream>>>(h, Wcat2, b2, sc1, sh1, A, C); // 7
    k_agg<<<AGB, 256, 0, stream>>>(A, (const h2*)C, off, deg, ssrc, h);          // 8
    k_statsf<<<1000, 128, 0, stream>>>(h, sums1, g2, be2, sc2, sh2, done + 1);   // 9

    // layer 3
    k_mm<HDIM, 32, true><<<MMG, 256, 0, stream>>>(h, Wcat3, b3, sc2, sh2, A, C); // 10
    k_agg<<<AGB, 256, 0, stream>>>(A, (const h2*)C, off, deg, ssrc, h);          // 11
    k_statsf<<<1000, 128, 0, stream>>>(h, sums2, g3, be3, sc3, sh3, done + 2);   // 12

    // fused pool + BN3 + linear + relu
    k_poolout<<<N_GRAPHS, 128, 0, stream>>>(h, sc3, sh3, Wl, bl, out);           // 13
}

// Round 9
// 563.639 us; speedup vs baseline: 1.0784x; 1.0401x over previous
//
#include <hip/hip_runtime.h>

#define N_NODES 50000
#define N_EDGES 800000
#define F_IN 24
#define HDIM 128
#define N_GRAPHS 100
#define BN_EPS 1e-5f
#define NBLK 196                          // ceil(N_NODES/256)
#define ROWS_PER_GRAPH (N_NODES / N_GRAPHS)
#define MM_GRID 782                       // ceil(N_NODES/64), 64-row tiles
#define HIST_BLKS ((N_EDGES + 255) / 256) // 3125
#define PREP_BLKS (F_IN + 2 * HDIM)       // 280

typedef _Float16 h2 __attribute__((ext_vector_type(2)));  // lowers to v_pk_* ops

// ---------------- node matmul (R6-verified shape: 64 rows x 128 cols, 8x4 tile) ---
// A(fp32) = bn(X)@(Wt-Wb)+b when y==0; C(fp16) = bn(X)@Wb when y==1. All-LDS K-loop.
template <int K, int KC, bool BN>
__global__ __launch_bounds__(256) void k_mm(const float* __restrict__ X,
                                            const float* __restrict__ Wcat,
                                            const float* __restrict__ bias,
                                            const float* __restrict__ scale,
                                            const float* __restrict__ shift,
                                            float* __restrict__ A, _Float16* __restrict__ C) {
    __shared__ float Xs[KC * 68];    // [kk][row], pad 64->68
    __shared__ float Ws[KC * 128];   // [kk][col]
    int tid = threadIdx.x;
    int row0 = blockIdx.x * 64;
    const bool isA = (blockIdx.y == 0);
    const int colbase = isA ? 0 : 128;
    int cg = tid & 31;        // col group: cols cg*4..cg*4+3
    int rg = tid >> 5;        // row group: rows rg*8..rg*8+7

    float acc[8][4];
#pragma unroll
    for (int ri = 0; ri < 8; ++ri)
#pragma unroll
        for (int ci = 0; ci < 4; ++ci)
            acc[ri][ci] = isA ? bias[cg * 4 + ci] : 0.f;

    for (int k0 = 0; k0 < K; k0 += KC) {
        __syncthreads();
        {
            const int C4 = KC / 4;
            for (int i = tid; i < 64 * C4; i += 256) {
                int c4 = i % C4, r = i / C4;
                int row = row0 + r;
                float4 v = make_float4(0.f, 0.f, 0.f, 0.f);
                if (row < N_NODES) v = *(const float4*)&X[row * K + k0 + c4 * 4];
                if (BN) {
                    int c = k0 + c4 * 4;
                    v.x = fmaxf(v.x * scale[c + 0] + shift[c + 0], 0.f);
                    v.y = fmaxf(v.y * scale[c + 1] + shift[c + 1], 0.f);
                    v.z = fmaxf(v.z * scale[c + 2] + shift[c + 2], 0.f);
                    v.w = fmaxf(v.w * scale[c + 3] + shift[c + 3], 0.f);
                }
                Xs[(c4 * 4 + 0) * 68 + r] = v.x;
                Xs[(c4 * 4 + 1) * 68 + r] = v.y;
                Xs[(c4 * 4 + 2) * 68 + r] = v.z;
                Xs[(c4 * 4 + 3) * 68 + r] = v.w;
            }
        }
        for (int i = tid; i < KC * 32; i += 256) {
            int c4 = i & 31, kr = i >> 5;
            *(float4*)&Ws[kr * 128 + c4 * 4] =
                *(const float4*)&Wcat[(k0 + kr) * 256 + colbase + c4 * 4];
        }
        __syncthreads();
#pragma unroll
        for (int kk = 0; kk < KC; ++kk) {
            float4 t0 = *(const float4*)&Xs[kk * 68 + rg * 8];
            float4 t1 = *(const float4*)&Xs[kk * 68 + rg * 8 + 4];
            float4 w = *(const float4*)&Ws[kk * 128 + cg * 4];
            float t[8] = {t0.x, t0.y, t0.z, t0.w, t1.x, t1.y, t1.z, t1.w};
            float wv[4] = {w.x, w.y, w.z, w.w};
#pragma unroll
            for (int ri = 0; ri < 8; ++ri)
#pragma unroll
                for (int ci = 0; ci < 4; ++ci)
                    acc[ri][ci] += t[ri] * wv[ci];
        }
    }

#pragma unroll
    for (int ri = 0; ri < 8; ++ri) {
        int row = row0 + rg * 8 + ri;
        if (row < N_NODES) {
            if (isA) {
                *(float4*)&A[row * HDIM + cg * 4] =
                    make_float4(acc[ri][0], acc[ri][1], acc[ri][2], acc[ri][3]);
            } else {
                union { h2 h[2]; uint2 u; } pk;
                pk.h[0] = h2{(_Float16)acc[ri][0], (_Float16)acc[ri][1]};
                pk.h[1] = h2{(_Float16)acc[ri][2], (_Float16)acc[ri][3]};
                *(uint2*)&C[row * HDIM + cg * 4] = pk.u;
            }
        }
    }
}

// ---------------- fused: weight prep + degree histogram (rank recorded) ----------
__global__ void k_pre(const float* __restrict__ W1, const float* __restrict__ W2,
                      const float* __restrict__ W3, float* __restrict__ Wc1,
                      float* __restrict__ Wc2, float* __restrict__ Wc3,
                      const int* __restrict__ dst, unsigned* __restrict__ deg,
                      unsigned* __restrict__ rank) {
    int b = blockIdx.x;
    int j = threadIdx.x;
    if (b < PREP_BLKS) {
        const float* W; float* Wc; int k, Fh;
        if (b < F_IN)             { W = W1; Wc = Wc1; k = b;               Fh = F_IN; }
        else if (b < F_IN + HDIM) { W = W2; Wc = Wc2; k = b - F_IN;        Fh = HDIM; }
        else                      { W = W3; Wc = Wc3; k = b - F_IN - HDIM; Fh = HDIM; }
        float wb = W[(k + Fh) * HDIM + (j & 127)];
        float wt = W[k * HDIM + (j & 127)];
        Wc[k * 256 + j] = (j < HDIM) ? (wt - wb) : wb;
    } else {
        int e = (b - PREP_BLKS) * 256 + j;
        if (e < N_EDGES) rank[e] = atomicAdd(&deg[dst[e]], 1u);  // rank = old count
    }
}

// ---------------- single-kernel scan: local scan -> publish(+1 bias) -> spin -----
// 196 blocks <= CU count => all co-resident; device-scope atomics for cross-XCD safety.
__global__ __launch_bounds__(256) void k_scanall(const unsigned* __restrict__ deg,
                                                 unsigned* __restrict__ bsum,  // zeroed
                                                 unsigned* __restrict__ off) {
    __shared__ unsigned s[256];
    int t = threadIdx.x;
    int b = blockIdx.x;
    int i = b * 256 + t;
    unsigned v = (i < N_NODES) ? deg[i] : 0u;
    s[t] = v;
    __syncthreads();
    for (int d = 1; d < 256; d <<= 1) {
        unsigned u = (t >= d) ? s[t - d] : 0u;
        __syncthreads();
        s[t] += u;
        __syncthreads();
    }
    unsigned locex = s[t] - v;           // in-block exclusive prefix
    if (t == 255) atomicExch(&bsum[b], s[255] + 1u);   // publish total, +1 = ready flag
    __syncthreads();                     // everyone done with s before reuse
    unsigned bs = 0;
    if (t < NBLK) {
        unsigned x;
        do { x = atomicAdd(&bsum[t], 0u); } while (x == 0u);
        bs = x - 1u;
    }
    s[t] = (t < NBLK) ? bs : 0u;
    __syncthreads();
    for (int d = 1; d < 256; d <<= 1) {
        unsigned u = (t >= d) ? s[t - d] : 0u;
        __syncthreads();
        s[t] += u;
        __syncthreads();
    }
    unsigned bexcl = (b == 0) ? 0u : s[b - 1];
    if (i < N_NODES) off[i] = bexcl + locex;
}

// ---------------- atomic-free scatter: pure fire-and-forget writes ---------------
__global__ void k_scatter(const int* __restrict__ src, const int* __restrict__ dst,
                          const unsigned* __restrict__ off, const unsigned* __restrict__ rank,
                          unsigned* __restrict__ ssrc) {
    int e = blockIdx.x * 256 + threadIdx.x;
    if (e < N_EDGES)
        ssrc[off[dst[e]] + rank[e]] = (unsigned)src[e];
}

// ---------------- aggregation: h[i][2l..2l+1] = relu(A + max_e C_fp16[src]) ------
__global__ __launch_bounds__(256) void k_agg(const float* __restrict__ A,
                                             const h2* __restrict__ Cc,   // 64 h2/row
                                             const unsigned* __restrict__ off,
                                             const unsigned* __restrict__ deg,
                                             const unsigned* __restrict__ ssrc,
                                             float* __restrict__ H) {
    __shared__ unsigned sl[4][64];
    int w = threadIdx.x >> 6;
    int lane = threadIdx.x & 63;
    int i = blockIdx.x * 4 + w;
    int d = (int)deg[i];
    unsigned o = off[i];
    union { unsigned short us[2]; h2 v; } ninf;
    ninf.us[0] = 0xFC00; ninf.us[1] = 0xFC00;
    h2 m2 = ninf.v;
    for (int base = 0; base < d; base += 64) {
        int cntc = min(64, d - base);
        if (lane < cntc) sl[w][lane] = ssrc[o + base + lane];
        int e = 0;
        for (; e + 8 <= cntc; e += 8) {
            unsigned s0 = sl[w][e + 0], s1 = sl[w][e + 1], s2 = sl[w][e + 2], s3 = sl[w][e + 3];
            unsigned s4 = sl[w][e + 4], s5 = sl[w][e + 5], s6 = sl[w][e + 6], s7 = sl[w][e + 7];
            h2 v0 = Cc[s0 * 64 + lane];
            h2 v1 = Cc[s1 * 64 + lane];
            h2 v2 = Cc[s2 * 64 + lane];
            h2 v3 = Cc[s3 * 64 + lane];
            h2 v4 = Cc[s4 * 64 + lane];
            h2 v5 = Cc[s5 * 64 + lane];
            h2 v6 = Cc[s6 * 64 + lane];
            h2 v7 = Cc[s7 * 64 + lane];
            h2 a0 = __builtin_elementwise_max(v0, v1);
            h2 a1 = __builtin_elementwise_max(v2, v3);
            h2 a2 = __builtin_elementwise_max(v4, v5);
            h2 a3 = __builtin_elementwise_max(v6, v7);
            h2 b0 = __builtin_elementwise_max(a0, a1);
            h2 b1 = __builtin_elementwise_max(a2, a3);
            m2 = __builtin_elementwise_max(m2, __builtin_elementwise_max(b0, b1));
        }
        if (e + 4 <= cntc) {
            unsigned s0 = sl[w][e + 0], s1 = sl[w][e + 1], s2 = sl[w][e + 2], s3 = sl[w][e + 3];
            h2 v0 = Cc[s0 * 64 + lane];
            h2 v1 = Cc[s1 * 64 + lane];
            h2 v2 = Cc[s2 * 64 + lane];
            h2 v3 = Cc[s3 * 64 + lane];
            h2 a0 = __builtin_elementwise_max(v0, v1);
            h2 a1 = __builtin_elementwise_max(v2, v3);
            m2 = __builtin_elementwise_max(m2, __builtin_elementwise_max(a0, a1));
            e += 4;
        }
        for (; e < cntc; ++e)
            m2 = __builtin_elementwise_max(m2, Cc[sl[w][e] * 64 + lane]);
    }
    float2 a = *(const float2*)&A[i * HDIM + lane * 2];
    float2 hv;
    hv.x = (d > 0) ? fmaxf(a.x + (float)m2.x, 0.f) : 0.f;
    hv.y = (d > 0) ? fmaxf(a.y + (float)m2.y, 0.f) : 0.f;
    *(float2*)&H[i * HDIM + lane * 2] = hv;
}

// ---------------- BN stats + last-block finstats ---------------------------------
__global__ __launch_bounds__(128) void k_statsf(const float* __restrict__ H,
                                                float* __restrict__ sums,   // zeroed
                                                const float* __restrict__ g,
                                                const float* __restrict__ be,
                                                float* __restrict__ sc, float* __restrict__ sh,
                                                unsigned* __restrict__ done) {  // zeroed
    int k = threadIdx.x;
    int b = blockIdx.x;          // 1000 blocks x 50 rows
    int lo = b * 50;
    float s = 0.f, s2 = 0.f;
    for (int r = lo; r < lo + 50; ++r) {
        float v = H[r * HDIM + k];
        s += v; s2 += v * v;
    }
    atomicAdd(&sums[k], s);
    atomicAdd(&sums[HDIM + k], s2);
    __threadfence();
    __syncthreads();
    __shared__ bool last;
    if (k == 0) last = (atomicAdd(done, 1u) == 999u);
    __syncthreads();
    if (last) {
        float S  = atomicAdd(&sums[k], 0.f);
        float S2 = atomicAdd(&sums[HDIM + k], 0.f);
        float mean = S / (float)N_NODES;
        float var = fmaxf(S2 / (float)N_NODES - mean * mean, 0.f);
        float scv = g[k] / sqrtf(var + BN_EPS);
        sc[k] = scv;
        sh[k] = be[k] - mean * scv;   // plain write: consumed by a later dispatch
    }
}

// ---------------- fused mean-pool + BN3-affine + linear + relu -------------------
__global__ __launch_bounds__(128) void k_poolout(const float* __restrict__ H,
                                                 const float* __restrict__ sc,
                                                 const float* __restrict__ sh,
                                                 const float* __restrict__ Wl,
                                                 const float* __restrict__ bl,
                                                 float* __restrict__ out) {
    int g = blockIdx.x;
    int k = threadIdx.x;
    const float* base = H + (size_t)g * ROWS_PER_GRAPH * HDIM;
    float s = 0.f;
#pragma unroll 4
    for (int r = 0; r < ROWS_PER_GRAPH; ++r) s += base[r * HDIM + k];
    float pb = sc[k] * (s * (1.f / (float)ROWS_PER_GRAPH)) + sh[k];
    float p = pb * Wl[k];
    __shared__ float red[2];
    for (int o = 32; o > 0; o >>= 1) p += __shfl_down(p, o);
    if ((k & 63) == 0) red[k >> 6] = p;
    __syncthreads();
    if (k == 0) out[g] = fmaxf(red[0] + red[1] + bl[0], 0.f);
}

// ---------------- launcher --------------------------------------------------------
extern "C" void kernel_launch(void* const* d_in, const int* in_sizes, int n_in,
                              void* d_out, int out_size, void* d_ws, size_t ws_size,
                              hipStream_t stream) {
    const float* x   = (const float*)d_in[0];
    const int* ei    = (const int*)d_in[1];
    const float* W1  = (const float*)d_in[3];
    const float* b1  = (const float*)d_in[4];
    const float* W2  = (const float*)d_in[5];
    const float* b2  = (const float*)d_in[6];
    const float* W3  = (const float*)d_in[7];
    const float* b3  = (const float*)d_in[8];
    const float* g1  = (const float*)d_in[9];
    const float* be1 = (const float*)d_in[10];
    const float* g2  = (const float*)d_in[11];
    const float* be2 = (const float*)d_in[12];
    const float* g3  = (const float*)d_in[13];
    const float* be3 = (const float*)d_in[14];
    const float* Wl  = (const float*)d_in[15];
    const float* bl  = (const float*)d_in[16];
    float* out = (float*)d_out;

    const int* srcp = ei;
    const int* dstp = ei + N_EDGES;

    // ---- workspace carve-up (256B aligned) ----
    char* ws = (char*)d_ws;
    size_t o = 0;
    auto alloc = [&](size_t bytes) -> void* {
        o = (o + 255) & ~(size_t)255;
        void* p = ws + o;
        o += bytes;
        return p;
    };
    float* A      = (float*)alloc((size_t)N_NODES * HDIM * 4);
    _Float16* C   = (_Float16*)alloc((size_t)N_NODES * HDIM * 2);
    float* h      = (float*)alloc((size_t)N_NODES * HDIM * 4);
    float* Wcat1  = (float*)alloc((size_t)F_IN * 256 * 4);
    float* Wcat2  = (float*)alloc((size_t)HDIM * 256 * 4);
    float* Wcat3  = (float*)alloc((size_t)HDIM * 256 * 4);
    // ---- zeroed region: deg .. done (single memset) ----
    unsigned* deg  = (unsigned*)alloc((size_t)N_NODES * 4);
    unsigned* bsum = (unsigned*)alloc((size_t)NBLK * 4);
    float* sums    = (float*)alloc(3 * 256 * 4);     // [layer][sum|sumsq]
    unsigned* done = (unsigned*)alloc(8 * 4);
    // ---- not zeroed (fully overwritten before read) ----
    unsigned* off  = (unsigned*)alloc((size_t)N_NODES * 4);
    unsigned* rank = (unsigned*)alloc((size_t)N_EDGES * 4);
    unsigned* ssrc = (unsigned*)alloc((size_t)N_EDGES * 4);
    float* scbuf   = (float*)alloc(6 * 128 * 4);     // sc1,sh1,sc2,sh2,sc3,sh3
    (void)ws_size; (void)n_in; (void)in_sizes; (void)out_size;

    float* sums0 = sums;        float* sums1 = sums + 256;  float* sums2 = sums + 512;
    float* sc1 = scbuf;         float* sh1 = scbuf + 128;
    float* sc2 = scbuf + 256;   float* sh2 = scbuf + 384;
    float* sc3 = scbuf + 512;   float* sh3 = scbuf + 640;

    size_t zlen = (size_t)((char*)(done + 8) - (char*)deg);
    (void)hipMemsetAsync(deg, 0, zlen, stream);                        // 1

    k_pre<<<PREP_BLKS + HIST_BLKS, 256, 0, stream>>>(W1, W2, W3, Wcat1, Wcat2, Wcat3,
                                                     dstp, deg, rank); // 2
    k_scanall<<<NBLK, 256, 0, stream>>>(deg, bsum, off);               // 3
    k_scatter<<<HIST_BLKS, 256, 0, stream>>>(srcp, dstp, off, rank, ssrc); // 4

    const dim3 MMG(MM_GRID, 2);
    const int AGB = N_NODES / 4;

    // layer 1
    k_mm<F_IN, F_IN, false><<<MMG, 256, 0, stream>>>(x, Wcat1, b1, nullptr, nullptr, A, C); // 5
    k_agg<<<AGB, 256, 0, stream>>>(A, (const h2*)C, off, deg, ssrc, h);                     // 6
    k_statsf<<<1000, 128, 0, stream>>>(h, sums0, g1, be1, sc1, sh1, done + 0);              // 7

    // layer 2
    k_mm<HDIM, 32, true><<<MMG, 256, 0, stream>>>(h, Wcat2, b2, sc1, sh1, A, C);            // 8
    k_agg<<<AGB, 256, 0, stream>>>(A, (const h2*)C, off, deg, ssrc, h);                     // 9
    k_statsf<<<1000, 128, 0, stream>>>(h, sums1, g2, be2, sc2, sh2, done + 1);              // 10

    // layer 3
    k_mm<HDIM, 32, true><<<MMG, 256, 0, stream>>>(h, Wcat3, b3, sc2, sh2, A, C);            // 11
    k_agg<<<AGB, 256, 0, stream>>>(A, (const h2*)C, off, deg, ssrc, h);                     // 12
    k_statsf<<<1000, 128, 0, stream>>>(h, sums2, g3, be3, sc3, sh3, done + 2);              // 13

    // fused pool + BN3 + linear + relu
    k_poolout<<<N_GRAPHS, 128, 0, stream>>>(h, sc3, sh3, Wl, bl, out);                      // 14
}

// Round 10
// 510.793 us; speedup vs baseline: 1.1900x; 1.1035x over previous
//
#include <hip/hip_runtime.h>

#define N_NODES 50000
#define N_EDGES 800000
#define F_IN 24
#define HDIM 128
#define N_GRAPHS 100
#define BN_EPS 1e-5f
#define NBLK 196                          // ceil(N_NODES/256)
#define ROWS_PER_GRAPH (N_NODES / N_GRAPHS)
#define MM_GRID 782                       // ceil(N_NODES/64), 64-row tiles
#define HIST_BLKS ((N_EDGES + 255) / 256) // 3125
#define PREP_BLKS (F_IN + 2 * HDIM)       // 280

typedef _Float16 h2 __attribute__((ext_vector_type(2)));   // packed fp16 pair
typedef _Float16 f16x8 __attribute__((ext_vector_type(8))); // MFMA A/B frag (4 VGPR)
typedef float f32x4 __attribute__((ext_vector_type(4)));    // MFMA C/D frag

// ---------------- layer-1 matmul (vector, K=24) -----------------------------------
// A(fp32) = X@(Wt-Wb)+b when y==0; C(fp16) = X@Wb when y==1.
template <int K, int KC>
__global__ __launch_bounds__(256) void k_mm1(const float* __restrict__ X,
                                             const float* __restrict__ Wcat,
                                             const float* __restrict__ bias,
                                             float* __restrict__ A, _Float16* __restrict__ C) {
    __shared__ float Xs[KC * 68];    // [kk][row], pad 64->68
    __shared__ float Ws[KC * 128];   // [kk][col]
    int tid = threadIdx.x;
    int row0 = blockIdx.x * 64;
    const bool isA = (blockIdx.y == 0);
    const int colbase = isA ? 0 : 128;
    int cg = tid & 31;
    int rg = tid >> 5;

    float acc[8][4];
#pragma unroll
    for (int ri = 0; ri < 8; ++ri)
#pragma unroll
        for (int ci = 0; ci < 4; ++ci)
            acc[ri][ci] = isA ? bias[cg * 4 + ci] : 0.f;

    for (int k0 = 0; k0 < K; k0 += KC) {
        __syncthreads();
        {
            const int C4 = KC / 4;
            for (int i = tid; i < 64 * C4; i += 256) {
                int c4 = i % C4, r = i / C4;
                int row = row0 + r;
                float4 v = make_float4(0.f, 0.f, 0.f, 0.f);
                if (row < N_NODES) v = *(const float4*)&X[row * K + k0 + c4 * 4];
                Xs[(c4 * 4 + 0) * 68 + r] = v.x;
                Xs[(c4 * 4 + 1) * 68 + r] = v.y;
                Xs[(c4 * 4 + 2) * 68 + r] = v.z;
                Xs[(c4 * 4 + 3) * 68 + r] = v.w;
            }
        }
        for (int i = tid; i < KC * 32; i += 256) {
            int c4 = i & 31, kr = i >> 5;
            *(float4*)&Ws[kr * 128 + c4 * 4] =
                *(const float4*)&Wcat[(k0 + kr) * 256 + colbase + c4 * 4];
        }
        __syncthreads();
#pragma unroll
        for (int kk = 0; kk < KC; ++kk) {
            float4 t0 = *(const float4*)&Xs[kk * 68 + rg * 8];
            float4 t1 = *(const float4*)&Xs[kk * 68 + rg * 8 + 4];
            float4 w = *(const float4*)&Ws[kk * 128 + cg * 4];
            float t[8] = {t0.x, t0.y, t0.z, t0.w, t1.x, t1.y, t1.z, t1.w};
            float wv[4] = {w.x, w.y, w.z, w.w};
#pragma unroll
            for (int ri = 0; ri < 8; ++ri)
#pragma unroll
                for (int ci = 0; ci < 4; ++ci)
                    acc[ri][ci] += t[ri] * wv[ci];
        }
    }

#pragma unroll
    for (int ri = 0; ri < 8; ++ri) {
        int row = row0 + rg * 8 + ri;
        if (row < N_NODES) {
            if (isA) {
                *(float4*)&A[row * HDIM + cg * 4] =
                    make_float4(acc[ri][0], acc[ri][1], acc[ri][2], acc[ri][3]);
            } else {
                union { h2 h[2]; uint2 u; } pk;
                pk.h[0] = h2{(_Float16)acc[ri][0], (_Float16)acc[ri][1]};
                pk.h[1] = h2{(_Float16)acc[ri][2], (_Float16)acc[ri][3]};
                *(uint2*)&C[row * HDIM + cg * 4] = pk.u;
            }
        }
    }
}

// ---------------- layers 2/3: MFMA matmul (fp16 in, fp32 acc) --------------------
// 64 rows x 128 cols/block, 4 waves x (16 rows x 8 col-tiles), K=128 in 4 chunks.
// Xh: A-frag-linear (16 frags of 1 KB, +16 B pad); Wh: B-frag-linear copy of Wf.
// Layouts [verified m89/m91]: A: m=lane&15,k=quad*8+j; B: n=lane&15,k=quad*8+j;
// D: col=lane&15, row=quad*4+reg.
__global__ __launch_bounds__(256) void k_mmf(const float* __restrict__ X,
                                             const _Float16* __restrict__ Wf, // 2 planes x 16384, frag-linear
                                             const float* __restrict__ bias,
                                             const float* __restrict__ scale,
                                             const float* __restrict__ shift,
                                             float* __restrict__ A, _Float16* __restrict__ C) {
    __shared__ _Float16 Xh[16 * 520];      // 16 frags x 1040 B
    __shared__ _Float16 Wh[128 * 128];     // 32 KB
    int tid = threadIdx.x;
    int lane = tid & 63, wv = tid >> 6;
    int row0 = blockIdx.x * 64;
    const bool isA = (blockIdx.y == 0);
    const _Float16* Wsrc = Wf + (isA ? 0 : 16384);

    // stage W: pure linear copy (global frag-order -> LDS), conflict-free
    {
        const uint4* s = (const uint4*)Wsrc;
        uint4* d = (uint4*)Wh;
        for (int i = tid; i < 2048; i += 256) d[i] = s[i];
    }
    // stage X with BN fold, into A-frag-linear (+pad) layout
    for (int i = tid; i < 64 * 32; i += 256) {
        int k4 = i & 31, rl = i >> 5;
        int row = row0 + rl;
        float4 v = make_float4(0.f, 0.f, 0.f, 0.f);
        if (row < N_NODES) v = *(const float4*)&X[row * HDIM + k4 * 4];
        int c = k4 * 4;
        v.x = fmaxf(v.x * scale[c + 0] + shift[c + 0], 0.f);
        v.y = fmaxf(v.y * scale[c + 1] + shift[c + 1], 0.f);
        v.z = fmaxf(v.z * scale[c + 2] + shift[c + 2], 0.f);
        v.w = fmaxf(v.w * scale[c + 3] + shift[c + 3], 0.f);
        int rt = rl >> 4, m = rl & 15, kc = k4 >> 3, q = (k4 >> 1) & 3, jh = k4 & 1;
        _Float16* d = Xh + (rt * 4 + kc) * 520 + (q * 16 + m) * 8 + jh * 4;
        d[0] = (_Float16)v.x; d[1] = (_Float16)v.y;
        d[2] = (_Float16)v.z; d[3] = (_Float16)v.w;
    }
    __syncthreads();

    int n = lane & 15, q = lane >> 4;
    f32x4 acc[8];
#pragma unroll
    for (int nt = 0; nt < 8; ++nt) {
        float b0 = isA ? bias[nt * 16 + n] : 0.f;
        acc[nt] = f32x4{b0, b0, b0, b0};
    }
#pragma unroll
    for (int kc = 0; kc < 4; ++kc) {
        f16x8 a = *(const f16x8*)(Xh + (wv * 4 + kc) * 520 + lane * 8);
#pragma unroll
        for (int nt = 0; nt < 8; ++nt) {
            f16x8 b = *(const f16x8*)(Wh + ((nt * 4 + kc) * 64 + lane) * 8);
            acc[nt] = __builtin_amdgcn_mfma_f32_16x16x32_f16(a, b, acc[nt], 0, 0, 0);
        }
    }
    // write out: row = row0 + wv*16 + q*4 + r, col = nt*16 + n
#pragma unroll
    for (int nt = 0; nt < 8; ++nt) {
#pragma unroll
        for (int r = 0; r < 4; ++r) {
            int row = row0 + wv * 16 + q * 4 + r;
            if (row < N_NODES) {
                int col = nt * 16 + n;
                if (isA) A[row * HDIM + col] = acc[nt][r];
                else     C[row * HDIM + col] = (_Float16)acc[nt][r];
            }
        }
    }
}

// ---------------- fused: weight prep + degree histogram (rank recorded) ----------
// Layer 1 -> fp32 Wcat1 [k][0:128]=Wt-Wb,[128:256]=Wb. Layers 2/3 -> fp16 frag-linear.
__global__ void k_pre(const float* __restrict__ W1, const float* __restrict__ W2,
                      const float* __restrict__ W3, float* __restrict__ Wcat1,
                      _Float16* __restrict__ Wf2, _Float16* __restrict__ Wf3,
                      const int* __restrict__ dst, unsigned* __restrict__ deg,
                      unsigned* __restrict__ rank) {
    int b = blockIdx.x;
    int j = threadIdx.x;
    if (b < F_IN) {
        float wb = W1[(b + F_IN) * HDIM + (j & 127)];
        float wt = W1[b * HDIM + (j & 127)];
        Wcat1[b * 256 + j] = (j < HDIM) ? (wt - wb) : wb;
    } else if (b < PREP_BLKS) {
        int idx = b - F_IN;
        int layer = idx >> 7;          // 0 -> W2, 1 -> W3
        int k = idx & 127;
        const float* W = layer ? W3 : W2;
        _Float16* Wf   = layer ? Wf3 : Wf2;
        int col = j & 127;
        float wt = W[k * HDIM + col];
        float wb = W[(k + HDIM) * HDIM + col];
        float v = (j < 128) ? (wt - wb) : wb;
        int plane = j >> 7;
        int nt = col >> 4, n = col & 15, kc = k >> 5, q = (k >> 3) & 3, jj = k & 7;
        int f = ((nt * 4 + kc) * 4 + q) * 128 + n * 8 + jj;
        Wf[plane * 16384 + f] = (_Float16)v;
    } else {
        int e = (b - PREP_BLKS) * 256 + j;
        if (e < N_EDGES) rank[e] = atomicAdd(&deg[dst[e]], 1u);  // rank = old count
    }
}

// ---------------- single-kernel scan: local scan -> publish(+1 bias) -> spin -----
__global__ __launch_bounds__(256) void k_scanall(const unsigned* __restrict__ deg,
                                                 unsigned* __restrict__ bsum,  // zeroed
                                                 unsigned* __restrict__ off) {
    __shared__ unsigned s[256];
    int t = threadIdx.x;
    int b = blockIdx.x;
    int i = b * 256 + t;
    unsigned v = (i < N_NODES) ? deg[i] : 0u;
    s[t] = v;
    __syncthreads();
    for (int d = 1; d < 256; d <<= 1) {
        unsigned u = (t >= d) ? s[t - d] : 0u;
        __syncthreads();
        s[t] += u;
        __syncthreads();
    }
    unsigned locex = s[t] - v;
    if (t == 255) atomicExch(&bsum[b], s[255] + 1u);
    __syncthreads();
    unsigned bs = 0;
    if (t < NBLK) {
        unsigned x;
        do { x = atomicAdd(&bsum[t], 0u); } while (x == 0u);
        bs = x - 1u;
    }
    s[t] = (t < NBLK) ? bs : 0u;
    __syncthreads();
    for (int d = 1; d < 256; d <<= 1) {
        unsigned u = (t >= d) ? s[t - d] : 0u;
        __syncthreads();
        s[t] += u;
        __syncthreads();
    }
    unsigned bexcl = (b == 0) ? 0u : s[b - 1];
    if (i < N_NODES) off[i] = bexcl + locex;
}

// ---------------- atomic-free scatter --------------------------------------------
__global__ void k_scatter(const int* __restrict__ src, const int* __restrict__ dst,
                          const unsigned* __restrict__ off, const unsigned* __restrict__ rank,
                          unsigned* __restrict__ ssrc) {
    int e = blockIdx.x * 256 + threadIdx.x;
    if (e < N_EDGES)
        ssrc[off[dst[e]] + rank[e]] = (unsigned)src[e];
}

// ---------------- aggregation: h[i][2l..2l+1] = relu(A + max_e C_fp16[src]) ------
__global__ __launch_bounds__(256) void k_agg(const float* __restrict__ A,
                                             const h2* __restrict__ Cc,   // 64 h2/row
                                             const unsigned* __restrict__ off,
                                             const unsigned* __restrict__ deg,
                                             const unsigned* __restrict__ ssrc,
                                             float* __restrict__ H) {
    __shared__ unsigned sl[4][64];
    int w = threadIdx.x >> 6;
    int lane = threadIdx.x & 63;
    int i = blockIdx.x * 4 + w;
    int d = (int)deg[i];
    unsigned o = off[i];
    union { unsigned short us[2]; h2 v; } ninf;
    ninf.us[0] = 0xFC00; ninf.us[1] = 0xFC00;
    h2 m2 = ninf.v;
    for (int base = 0; base < d; base += 64) {
        int cntc = min(64, d - base);
        if (lane < cntc) sl[w][lane] = ssrc[o + base + lane];
        int e = 0;
        for (; e + 8 <= cntc; e += 8) {
            unsigned s0 = sl[w][e + 0], s1 = sl[w][e + 1], s2 = sl[w][e + 2], s3 = sl[w][e + 3];
            unsigned s4 = sl[w][e + 4], s5 = sl[w][e + 5], s6 = sl[w][e + 6], s7 = sl[w][e + 7];
            h2 v0 = Cc[s0 * 64 + lane];
            h2 v1 = Cc[s1 * 64 + lane];
            h2 v2 = Cc[s2 * 64 + lane];
            h2 v3 = Cc[s3 * 64 + lane];
            h2 v4 = Cc[s4 * 64 + lane];
            h2 v5 = Cc[s5 * 64 + lane];
            h2 v6 = Cc[s6 * 64 + lane];
            h2 v7 = Cc[s7 * 64 + lane];
            h2 a0 = __builtin_elementwise_max(v0, v1);
            h2 a1 = __builtin_elementwise_max(v2, v3);
            h2 a2 = __builtin_elementwise_max(v4, v5);
            h2 a3 = __builtin_elementwise_max(v6, v7);
            h2 b0 = __builtin_elementwise_max(a0, a1);
            h2 b1 = __builtin_elementwise_max(a2, a3);
            m2 = __builtin_elementwise_max(m2, __builtin_elementwise_max(b0, b1));
        }
        if (e + 4 <= cntc) {
            unsigned s0 = sl[w][e + 0], s1 = sl[w][e + 1], s2 = sl[w][e + 2], s3 = sl[w][e + 3];
            h2 v0 = Cc[s0 * 64 + lane];
            h2 v1 = Cc[s1 * 64 + lane];
            h2 v2 = Cc[s2 * 64 + lane];
            h2 v3 = Cc[s3 * 64 + lane];
            h2 a0 = __builtin_elementwise_max(v0, v1);
            h2 a1 = __builtin_elementwise_max(v2, v3);
            m2 = __builtin_elementwise_max(m2, __builtin_elementwise_max(a0, a1));
            e += 4;
        }
        for (; e < cntc; ++e)
            m2 = __builtin_elementwise_max(m2, Cc[sl[w][e] * 64 + lane]);
    }
    float2 a = *(const float2*)&A[i * HDIM + lane * 2];
    float2 hv;
    hv.x = (d > 0) ? fmaxf(a.x + (float)m2.x, 0.f) : 0.f;
    hv.y = (d > 0) ? fmaxf(a.y + (float)m2.y, 0.f) : 0.f;
    *(float2*)&H[i * HDIM + lane * 2] = hv;
}

// ---------------- BN stats + last-block finstats ---------------------------------
__global__ __launch_bounds__(128) void k_statsf(const float* __restrict__ H,
                                                float* __restrict__ sums,   // zeroed
                                                const float* __restrict__ g,
                                                const float* __restrict__ be,
                                                float* __restrict__ sc, float* __restrict__ sh,
                                                unsigned* __restrict__ done) {  // zeroed
    int k = threadIdx.x;
    int b = blockIdx.x;          // 1000 blocks x 50 rows
    int lo = b * 50;
    float s = 0.f, s2 = 0.f;
    for (int r = lo; r < lo + 50; ++r) {
        float v = H[r * HDIM + k];
        s += v; s2 += v * v;
    }
    atomicAdd(&sums[k], s);
    atomicAdd(&sums[HDIM + k], s2);
    __threadfence();
    __syncthreads();
    __shared__ bool last;
    if (k == 0) last = (atomicAdd(done, 1u) == 999u);
    __syncthreads();
    if (last) {
        float S  = atomicAdd(&sums[k], 0.f);
        float S2 = atomicAdd(&sums[HDIM + k], 0.f);
        float mean = S / (float)N_NODES;
        float var = fmaxf(S2 / (float)N_NODES - mean * mean, 0.f);
        float scv = g[k] / sqrtf(var + BN_EPS);
        sc[k] = scv;
        sh[k] = be[k] - mean * scv;
    }
}

// ---------------- fused mean-pool + BN3-affine + linear + relu -------------------
__global__ __launch_bounds__(128) void k_poolout(const float* __restrict__ H,
                                                 const float* __restrict__ sc,
                                                 const float* __restrict__ sh,
                                                 const float* __restrict__ Wl,
                                                 const float* __restrict__ bl,
                                                 float* __restrict__ out) {
    int g = blockIdx.x;
    int k = threadIdx.x;
    const float* base = H + (size_t)g * ROWS_PER_GRAPH * HDIM;
    float s = 0.f;
#pragma unroll 4
    for (int r = 0; r < ROWS_PER_GRAPH; ++r) s += base[r * HDIM + k];
    float pb = sc[k] * (s * (1.f / (float)ROWS_PER_GRAPH)) + sh[k];
    float p = pb * Wl[k];
    __shared__ float red[2];
    for (int o = 32; o > 0; o >>= 1) p += __shfl_down(p, o);
    if ((k & 63) == 0) red[k >> 6] = p;
    __syncthreads();
    if (k == 0) out[g] = fmaxf(red[0] + red[1] + bl[0], 0.f);
}

// ---------------- launcher --------------------------------------------------------
extern "C" void kernel_launch(void* const* d_in, const int* in_sizes, int n_in,
                              void* d_out, int out_size, void* d_ws, size_t ws_size,
                              hipStream_t stream) {
    const float* x   = (const float*)d_in[0];
    const int* ei    = (const int*)d_in[1];
    const float* W1  = (const float*)d_in[3];
    const float* b1  = (const float*)d_in[4];
    const float* W2  = (const float*)d_in[5];
    const float* b2  = (const float*)d_in[6];
    const float* W3  = (const float*)d_in[7];
    const float* b3  = (const float*)d_in[8];
    const float* g1  = (const float*)d_in[9];
    const float* be1 = (const float*)d_in[10];
    const float* g2  = (const float*)d_in[11];
    const float* be2 = (const float*)d_in[12];
    const float* g3  = (const float*)d_in[13];
    const float* be3 = (const float*)d_in[14];
    const float* Wl  = (const float*)d_in[15];
    const float* bl  = (const float*)d_in[16];
    float* out = (float*)d_out;

    const int* srcp = ei;
    const int* dstp = ei + N_EDGES;

    // ---- workspace carve-up (256B aligned) ----
    char* ws = (char*)d_ws;
    size_t o = 0;
    auto alloc = [&](size_t bytes) -> void* {
        o = (o + 255) & ~(size_t)255;
        void* p = ws + o;
        o += bytes;
        return p;
    };
    float* A      = (float*)alloc((size_t)N_NODES * HDIM * 4);
    _Float16* C   = (_Float16*)alloc((size_t)N_NODES * HDIM * 2);
    float* h      = (float*)alloc((size_t)N_NODES * HDIM * 4);
    float* Wcat1  = (float*)alloc((size_t)F_IN * 256 * 4);
    _Float16* Wf2 = (_Float16*)alloc((size_t)2 * 16384 * 2);
    _Float16* Wf3 = (_Float16*)alloc((size_t)2 * 16384 * 2);
    // ---- zeroed region: deg .. done (single memset) ----
    unsigned* deg  = (unsigned*)alloc((size_t)N_NODES * 4);
    unsigned* bsum = (unsigned*)alloc((size_t)NBLK * 4);
    float* sums    = (float*)alloc(3 * 256 * 4);
    unsigned* done = (unsigned*)alloc(8 * 4);
    // ---- not zeroed (fully overwritten before read) ----
    unsigned* off  = (unsigned*)alloc((size_t)N_NODES * 4);
    unsigned* rank = (unsigned*)alloc((size_t)N_EDGES * 4);
    unsigned* ssrc = (unsigned*)alloc((size_t)N_EDGES * 4);
    float* scbuf   = (float*)alloc(6 * 128 * 4);
    (void)ws_size; (void)n_in; (void)in_sizes; (void)out_size;

    float* sums0 = sums;        float* sums1 = sums + 256;  float* sums2 = sums + 512;
    float* sc1 = scbuf;         float* sh1 = scbuf + 128;
    float* sc2 = scbuf + 256;   float* sh2 = scbuf + 384;
    float* sc3 = scbuf + 512;   float* sh3 = scbuf + 640;

    size_t zlen = (size_t)((char*)(done + 8) - (char*)deg);
    (void)hipMemsetAsync(deg, 0, zlen, stream);                        // 1

    k_pre<<<PREP_BLKS + HIST_BLKS, 256, 0, stream>>>(W1, W2, W3, Wcat1, Wf2, Wf3,
                                                     dstp, deg, rank); // 2
    k_scanall<<<NBLK, 256, 0, stream>>>(deg, bsum, off);               // 3
    k_scatter<<<HIST_BLKS, 256, 0, stream>>>(srcp, dstp, off, rank, ssrc); // 4

    const dim3 MMG(MM_GRID, 2);
    const int AGB = N_NODES / 4;

    // layer 1
    k_mm1<F_IN, F_IN><<<MMG, 256, 0, stream>>>(x, Wcat1, b1, A, C);                 // 5
    k_agg<<<AGB, 256, 0, stream>>>(A, (const h2*)C, off, deg, ssrc, h);             // 6
    k_statsf<<<1000, 128, 0, stream>>>(h, sums0, g1, be1, sc1, sh1, done + 0);      // 7

    // layer 2 (MFMA)
    k_mmf<<<MMG, 256, 0, stream>>>(h, Wf2, b2, sc1, sh1, A, C);                     // 8
    k_agg<<<AGB, 256, 0, stream>>>(A, (const h2*)C, off, deg, ssrc, h);             // 9
    k_statsf<<<1000, 128, 0, stream>>>(h, sums1, g2, be2, sc2, sh2, done + 1);      // 10

    // layer 3 (MFMA)
    k_mmf<<<MMG, 256, 0, stream>>>(h, Wf3, b3, sc2, sh2, A, C);                     // 11
    k_agg<<<AGB, 256, 0, stream>>>(A, (const h2*)C, off, deg, ssrc, h);             // 12
    k_statsf<<<1000, 128, 0, stream>>>(h, sums2, g3, be3, sc3, sh3, done + 2);      // 13

    // fused pool + BN3 + linear + relu
    k_poolout<<<N_GRAPHS, 128, 0, stream>>>(h, sc3, sh3, Wl, bl, out);              // 14
}

// Round 11
// 494.041 us; speedup vs baseline: 1.2303x; 1.0339x over previous
//
#include <hip/hip_runtime.h>

#define N_NODES 50000
#define N_EDGES 800000
#define F_IN 24
#define HDIM 128
#define N_GRAPHS 100
#define BN_EPS 1e-5f
#define NBLK 196                          // ceil(N_NODES/256)
#define ROWS_PER_GRAPH (N_NODES / N_GRAPHS)
#define MM_GRID 782                       // ceil(N_NODES/64), 64-row tiles
#define HIST_BLKS ((N_EDGES + 255) / 256) // 3125
#define PREP_BLKS (F_IN + 2 * HDIM)       // 280
#define SSTR 32                           // 32 floats = 128 B: one cache line per channel
#define SUMS_PER_LAYER (256 * SSTR)       // 8192 floats = 32 KB

typedef _Float16 h2 __attribute__((ext_vector_type(2)));   // packed fp16 pair
typedef _Float16 f16x8 __attribute__((ext_vector_type(8))); // MFMA A/B frag (4 VGPR)
typedef float f32x4 __attribute__((ext_vector_type(4)));    // MFMA C/D frag

// ---------------- layer-1 matmul (vector, K=24) -----------------------------------
// A(fp32) = X@(Wt-Wb)+b when y==0; C(fp16) = X@Wb when y==1.
template <int K, int KC>
__global__ __launch_bounds__(256) void k_mm1(const float* __restrict__ X,
                                             const float* __restrict__ Wcat,
                                             const float* __restrict__ bias,
                                             float* __restrict__ A, _Float16* __restrict__ C) {
    __shared__ float Xs[KC * 68];    // [kk][row], pad 64->68
    __shared__ float Ws[KC * 128];   // [kk][col]
    int tid = threadIdx.x;
    int row0 = blockIdx.x * 64;
    const bool isA = (blockIdx.y == 0);
    const int colbase = isA ? 0 : 128;
    int cg = tid & 31;
    int rg = tid >> 5;

    float acc[8][4];
#pragma unroll
    for (int ri = 0; ri < 8; ++ri)
#pragma unroll
        for (int ci = 0; ci < 4; ++ci)
            acc[ri][ci] = isA ? bias[cg * 4 + ci] : 0.f;

    for (int k0 = 0; k0 < K; k0 += KC) {
        __syncthreads();
        {
            const int C4 = KC / 4;
            for (int i = tid; i < 64 * C4; i += 256) {
                int c4 = i % C4, r = i / C4;
                int row = row0 + r;
                float4 v = make_float4(0.f, 0.f, 0.f, 0.f);
                if (row < N_NODES) v = *(const float4*)&X[row * K + k0 + c4 * 4];
                Xs[(c4 * 4 + 0) * 68 + r] = v.x;
                Xs[(c4 * 4 + 1) * 68 + r] = v.y;
                Xs[(c4 * 4 + 2) * 68 + r] = v.z;
                Xs[(c4 * 4 + 3) * 68 + r] = v.w;
            }
        }
        for (int i = tid; i < KC * 32; i += 256) {
            int c4 = i & 31, kr = i >> 5;
            *(float4*)&Ws[kr * 128 + c4 * 4] =
                *(const float4*)&Wcat[(k0 + kr) * 256 + colbase + c4 * 4];
        }
        __syncthreads();
#pragma unroll
        for (int kk = 0; kk < KC; ++kk) {
            float4 t0 = *(const float4*)&Xs[kk * 68 + rg * 8];
            float4 t1 = *(const float4*)&Xs[kk * 68 + rg * 8 + 4];
            float4 w = *(const float4*)&Ws[kk * 128 + cg * 4];
            float t[8] = {t0.x, t0.y, t0.z, t0.w, t1.x, t1.y, t1.z, t1.w};
            float wv[4] = {w.x, w.y, w.z, w.w};
#pragma unroll
            for (int ri = 0; ri < 8; ++ri)
#pragma unroll
                for (int ci = 0; ci < 4; ++ci)
                    acc[ri][ci] += t[ri] * wv[ci];
        }
    }

#pragma unroll
    for (int ri = 0; ri < 8; ++ri) {
        int row = row0 + rg * 8 + ri;
        if (row < N_NODES) {
            if (isA) {
                *(float4*)&A[row * HDIM + cg * 4] =
                    make_float4(acc[ri][0], acc[ri][1], acc[ri][2], acc[ri][3]);
            } else {
                union { h2 h[2]; uint2 u; } pk;
                pk.h[0] = h2{(_Float16)acc[ri][0], (_Float16)acc[ri][1]};
                pk.h[1] = h2{(_Float16)acc[ri][2], (_Float16)acc[ri][3]};
                *(uint2*)&C[row * HDIM + cg * 4] = pk.u;
            }
        }
    }
}

// ---------------- layers 2/3: MFMA matmul (fp16 in, fp32 acc) --------------------
__global__ __launch_bounds__(256) void k_mmf(const float* __restrict__ X,
                                             const _Float16* __restrict__ Wf, // 2 planes x 16384, frag-linear
                                             const float* __restrict__ bias,
                                             const float* __restrict__ scale,
                                             const float* __restrict__ shift,
                                             float* __restrict__ A, _Float16* __restrict__ C) {
    __shared__ _Float16 Xh[16 * 520];      // 16 frags x 1040 B
    __shared__ _Float16 Wh[128 * 128];     // 32 KB
    int tid = threadIdx.x;
    int lane = tid & 63, wv = tid >> 6;
    int row0 = blockIdx.x * 64;
    const bool isA = (blockIdx.y == 0);
    const _Float16* Wsrc = Wf + (isA ? 0 : 16384);

    {
        const uint4* s = (const uint4*)Wsrc;
        uint4* d = (uint4*)Wh;
        for (int i = tid; i < 2048; i += 256) d[i] = s[i];
    }
    for (int i = tid; i < 64 * 32; i += 256) {
        int k4 = i & 31, rl = i >> 5;
        int row = row0 + rl;
        float4 v = make_float4(0.f, 0.f, 0.f, 0.f);
        if (row < N_NODES) v = *(const float4*)&X[row * HDIM + k4 * 4];
        int c = k4 * 4;
        v.x = fmaxf(v.x * scale[c + 0] + shift[c + 0], 0.f);
        v.y = fmaxf(v.y * scale[c + 1] + shift[c + 1], 0.f);
        v.z = fmaxf(v.z * scale[c + 2] + shift[c + 2], 0.f);
        v.w = fmaxf(v.w * scale[c + 3] + shift[c + 3], 0.f);
        int rt = rl >> 4, m = rl & 15, kc = k4 >> 3, q = (k4 >> 1) & 3, jh = k4 & 1;
        _Float16* d = Xh + (rt * 4 + kc) * 520 + (q * 16 + m) * 8 + jh * 4;
        d[0] = (_Float16)v.x; d[1] = (_Float16)v.y;
        d[2] = (_Float16)v.z; d[3] = (_Float16)v.w;
    }
    __syncthreads();

    int n = lane & 15, q = lane >> 4;
    f32x4 acc[8];
#pragma unroll
    for (int nt = 0; nt < 8; ++nt) {
        float b0 = isA ? bias[nt * 16 + n] : 0.f;
        acc[nt] = f32x4{b0, b0, b0, b0};
    }
#pragma unroll
    for (int kc = 0; kc < 4; ++kc) {
        f16x8 a = *(const f16x8*)(Xh + (wv * 4 + kc) * 520 + lane * 8);
#pragma unroll
        for (int nt = 0; nt < 8; ++nt) {
            f16x8 b = *(const f16x8*)(Wh + ((nt * 4 + kc) * 64 + lane) * 8);
            acc[nt] = __builtin_amdgcn_mfma_f32_16x16x32_f16(a, b, acc[nt], 0, 0, 0);
        }
    }
#pragma unroll
    for (int nt = 0; nt < 8; ++nt) {
#pragma unroll
        for (int r = 0; r < 4; ++r) {
            int row = row0 + wv * 16 + q * 4 + r;
            if (row < N_NODES) {
                int col = nt * 16 + n;
                if (isA) A[row * HDIM + col] = acc[nt][r];
                else     C[row * HDIM + col] = (_Float16)acc[nt][r];
            }
        }
    }
}

// ---------------- fused: weight prep + degree histogram (rank recorded) ----------
__global__ void k_pre(const float* __restrict__ W1, const float* __restrict__ W2,
                      const float* __restrict__ W3, float* __restrict__ Wcat1,
                      _Float16* __restrict__ Wf2, _Float16* __restrict__ Wf3,
                      const int* __restrict__ dst, unsigned* __restrict__ deg,
                      unsigned* __restrict__ rank) {
    int b = blockIdx.x;
    int j = threadIdx.x;
    if (b < F_IN) {
        float wb = W1[(b + F_IN) * HDIM + (j & 127)];
        float wt = W1[b * HDIM + (j & 127)];
        Wcat1[b * 256 + j] = (j < HDIM) ? (wt - wb) : wb;
    } else if (b < PREP_BLKS) {
        int idx = b - F_IN;
        int layer = idx >> 7;
        int k = idx & 127;
        const float* W = layer ? W3 : W2;
        _Float16* Wf   = layer ? Wf3 : Wf2;
        int col = j & 127;
        float wt = W[k * HDIM + col];
        float wb = W[(k + HDIM) * HDIM + col];
        float v = (j < 128) ? (wt - wb) : wb;
        int plane = j >> 7;
        int nt = col >> 4, n = col & 15, kc = k >> 5, q = (k >> 3) & 3, jj = k & 7;
        int f = ((nt * 4 + kc) * 4 + q) * 128 + n * 8 + jj;
        Wf[plane * 16384 + f] = (_Float16)v;
    } else {
        int e = (b - PREP_BLKS) * 256 + j;
        if (e < N_EDGES) rank[e] = atomicAdd(&deg[dst[e]], 1u);
    }
}

// ---------------- single-kernel scan ---------------------------------------------
__global__ __launch_bounds__(256) void k_scanall(const unsigned* __restrict__ deg,
                                                 unsigned* __restrict__ bsum,  // zeroed
                                                 unsigned* __restrict__ off) {
    __shared__ unsigned s[256];
    int t = threadIdx.x;
    int b = blockIdx.x;
    int i = b * 256 + t;
    unsigned v = (i < N_NODES) ? deg[i] : 0u;
    s[t] = v;
    __syncthreads();
    for (int d = 1; d < 256; d <<= 1) {
        unsigned u = (t >= d) ? s[t - d] : 0u;
        __syncthreads();
        s[t] += u;
        __syncthreads();
    }
    unsigned locex = s[t] - v;
    if (t == 255) atomicExch(&bsum[b], s[255] + 1u);
    __syncthreads();
    unsigned bs = 0;
    if (t < NBLK) {
        unsigned x;
        do { x = atomicAdd(&bsum[t], 0u); } while (x == 0u);
        bs = x - 1u;
    }
    s[t] = (t < NBLK) ? bs : 0u;
    __syncthreads();
    for (int d = 1; d < 256; d <<= 1) {
        unsigned u = (t >= d) ? s[t - d] : 0u;
        __syncthreads();
        s[t] += u;
        __syncthreads();
    }
    unsigned bexcl = (b == 0) ? 0u : s[b - 1];
    if (i < N_NODES) off[i] = bexcl + locex;
}

// ---------------- atomic-free scatter --------------------------------------------
__global__ void k_scatter(const int* __restrict__ src, const int* __restrict__ dst,
                          const unsigned* __restrict__ off, const unsigned* __restrict__ rank,
                          unsigned* __restrict__ ssrc) {
    int e = blockIdx.x * 256 + threadIdx.x;
    if (e < N_EDGES)
        ssrc[off[dst[e]] + rank[e]] = (unsigned)src[e];
}

// ---------------- aggregation: h[i][2l..2l+1] = relu(A + max_e C_fp16[src]) ------
__global__ __launch_bounds__(256) void k_agg(const float* __restrict__ A,
                                             const h2* __restrict__ Cc,   // 64 h2/row
                                             const unsigned* __restrict__ off,
                                             const unsigned* __restrict__ deg,
                                             const unsigned* __restrict__ ssrc,
                                             float* __restrict__ H) {
    __shared__ unsigned sl[4][64];
    int w = threadIdx.x >> 6;
    int lane = threadIdx.x & 63;
    int i = blockIdx.x * 4 + w;
    int d = (int)deg[i];
    unsigned o = off[i];
    union { unsigned short us[2]; h2 v; } ninf;
    ninf.us[0] = 0xFC00; ninf.us[1] = 0xFC00;
    h2 m2 = ninf.v;
    for (int base = 0; base < d; base += 64) {
        int cntc = min(64, d - base);
        if (lane < cntc) sl[w][lane] = ssrc[o + base + lane];
        int e = 0;
        for (; e + 8 <= cntc; e += 8) {
            unsigned s0 = sl[w][e + 0], s1 = sl[w][e + 1], s2 = sl[w][e + 2], s3 = sl[w][e + 3];
            unsigned s4 = sl[w][e + 4], s5 = sl[w][e + 5], s6 = sl[w][e + 6], s7 = sl[w][e + 7];
            h2 v0 = Cc[s0 * 64 + lane];
            h2 v1 = Cc[s1 * 64 + lane];
            h2 v2 = Cc[s2 * 64 + lane];
            h2 v3 = Cc[s3 * 64 + lane];
            h2 v4 = Cc[s4 * 64 + lane];
            h2 v5 = Cc[s5 * 64 + lane];
            h2 v6 = Cc[s6 * 64 + lane];
            h2 v7 = Cc[s7 * 64 + lane];
            h2 a0 = __builtin_elementwise_max(v0, v1);
            h2 a1 = __builtin_elementwise_max(v2, v3);
            h2 a2 = __builtin_elementwise_max(v4, v5);
            h2 a3 = __builtin_elementwise_max(v6, v7);
            h2 b0 = __builtin_elementwise_max(a0, a1);
            h2 b1 = __builtin_elementwise_max(a2, a3);
            m2 = __builtin_elementwise_max(m2, __builtin_elementwise_max(b0, b1));
        }
        if (e + 4 <= cntc) {
            unsigned s0 = sl[w][e + 0], s1 = sl[w][e + 1], s2 = sl[w][e + 2], s3 = sl[w][e + 3];
            h2 v0 = Cc[s0 * 64 + lane];
            h2 v1 = Cc[s1 * 64 + lane];
            h2 v2 = Cc[s2 * 64 + lane];
            h2 v3 = Cc[s3 * 64 + lane];
            h2 a0 = __builtin_elementwise_max(v0, v1);
            h2 a1 = __builtin_elementwise_max(v2, v3);
            m2 = __builtin_elementwise_max(m2, __builtin_elementwise_max(a0, a1));
            e += 4;
        }
        for (; e < cntc; ++e)
            m2 = __builtin_elementwise_max(m2, Cc[sl[w][e] * 64 + lane]);
    }
    float2 a = *(const float2*)&A[i * HDIM + lane * 2];
    float2 hv;
    hv.x = (d > 0) ? fmaxf(a.x + (float)m2.x, 0.f) : 0.f;
    hv.y = (d > 0) ? fmaxf(a.y + (float)m2.y, 0.f) : 0.f;
    *(float2*)&H[i * HDIM + lane * 2] = hv;
}

// ---------------- BN stats + last-block finstats ---------------------------------
// sums layout: channel k -> sums[k*SSTR] (sum), sums[(128+k)*SSTR] (sumsq).
// 128 B per accumulator = one cache line each: no same-line atomic serialization.
__global__ __launch_bounds__(128) void k_statsf(const float* __restrict__ H,
                                                float* __restrict__ sums,   // zeroed
                                                const float* __restrict__ g,
                                                const float* __restrict__ be,
                                                float* __restrict__ sc, float* __restrict__ sh,
                                                unsigned* __restrict__ done) {  // zeroed
    int k = threadIdx.x;
    int b = blockIdx.x;          // 1000 blocks x 50 rows
    int lo = b * 50;
    float s = 0.f, s2 = 0.f;
    for (int r = lo; r < lo + 50; ++r) {
        float v = H[r * HDIM + k];
        s += v; s2 += v * v;
    }
    atomicAdd(&sums[k * SSTR], s);
    atomicAdd(&sums[(128 + k) * SSTR], s2);
    __threadfence();
    __syncthreads();
    __shared__ bool last;
    if (k == 0) last = (atomicAdd(done, 1u) == 999u);
    __syncthreads();
    if (last) {
        float S  = atomicAdd(&sums[k * SSTR], 0.f);
        float S2 = atomicAdd(&sums[(128 + k) * SSTR], 0.f);
        float mean = S / (float)N_NODES;
        float var = fmaxf(S2 / (float)N_NODES - mean * mean, 0.f);
        float scv = g[k] / sqrtf(var + BN_EPS);
        sc[k] = scv;
        sh[k] = be[k] - mean * scv;
    }
}

// ---------------- fused mean-pool + BN3-affine + linear + relu -------------------
__global__ __launch_bounds__(128) void k_poolout(const float* __restrict__ H,
                                                 const float* __restrict__ sc,
                                                 const float* __restrict__ sh,
                                                 const float* __restrict__ Wl,
                                                 const float* __restrict__ bl,
                                                 float* __restrict__ out) {
    int g = blockIdx.x;
    int k = threadIdx.x;
    const float* base = H + (size_t)g * ROWS_PER_GRAPH * HDIM;
    float s = 0.f;
#pragma unroll 4
    for (int r = 0; r < ROWS_PER_GRAPH; ++r) s += base[r * HDIM + k];
    float pb = sc[k] * (s * (1.f / (float)ROWS_PER_GRAPH)) + sh[k];
    float p = pb * Wl[k];
    __shared__ float red[2];
    for (int o = 32; o > 0; o >>= 1) p += __shfl_down(p, o);
    if ((k & 63) == 0) red[k >> 6] = p;
    __syncthreads();
    if (k == 0) out[g] = fmaxf(red[0] + red[1] + bl[0], 0.f);
}

// ---------------- launcher --------------------------------------------------------
extern "C" void kernel_launch(void* const* d_in, const int* in_sizes, int n_in,
                              void* d_out, int out_size, void* d_ws, size_t ws_size,
                              hipStream_t stream) {
    const float* x   = (const float*)d_in[0];
    const int* ei    = (const int*)d_in[1];
    const float* W1  = (const float*)d_in[3];
    const float* b1  = (const float*)d_in[4];
    const float* W2  = (const float*)d_in[5];
    const float* b2  = (const float*)d_in[6];
    const float* W3  = (const float*)d_in[7];
    const float* b3  = (const float*)d_in[8];
    const float* g1  = (const float*)d_in[9];
    const float* be1 = (const float*)d_in[10];
    const float* g2  = (const float*)d_in[11];
    const float* be2 = (const float*)d_in[12];
    const float* g3  = (const float*)d_in[13];
    const float* be3 = (const float*)d_in[14];
    const float* Wl  = (const float*)d_in[15];
    const float* bl  = (const float*)d_in[16];
    float* out = (float*)d_out;

    const int* srcp = ei;
    const int* dstp = ei + N_EDGES;

    // ---- workspace carve-up (256B aligned) ----
    char* ws = (char*)d_ws;
    size_t o = 0;
    auto alloc = [&](size_t bytes) -> void* {
        o = (o + 255) & ~(size_t)255;
        void* p = ws + o;
        o += bytes;
        return p;
    };
    float* A      = (float*)alloc((size_t)N_NODES * HDIM * 4);
    _Float16* C   = (_Float16*)alloc((size_t)N_NODES * HDIM * 2);
    float* h      = (float*)alloc((size_t)N_NODES * HDIM * 4);
    float* Wcat1  = (float*)alloc((size_t)F_IN * 256 * 4);
    _Float16* Wf2 = (_Float16*)alloc((size_t)2 * 16384 * 2);
    _Float16* Wf3 = (_Float16*)alloc((size_t)2 * 16384 * 2);
    // ---- zeroed region: deg .. done (single memset) ----
    unsigned* deg  = (unsigned*)alloc((size_t)N_NODES * 4);
    unsigned* bsum = (unsigned*)alloc((size_t)NBLK * 4);
    float* sums    = (float*)alloc((size_t)3 * SUMS_PER_LAYER * 4);  // 96 KB padded
    unsigned* done = (unsigned*)alloc(8 * 4);
    // ---- not zeroed (fully overwritten before read) ----
    unsigned* off  = (unsigned*)alloc((size_t)N_NODES * 4);
    unsigned* rank = (unsigned*)alloc((size_t)N_EDGES * 4);
    unsigned* ssrc = (unsigned*)alloc((size_t)N_EDGES * 4);
    float* scbuf   = (float*)alloc(6 * 128 * 4);
    (void)ws_size; (void)n_in; (void)in_sizes; (void)out_size;

    float* sums0 = sums;
    float* sums1 = sums + SUMS_PER_LAYER;
    float* sums2 = sums + 2 * SUMS_PER_LAYER;
    float* sc1 = scbuf;         float* sh1 = scbuf + 128;
    float* sc2 = scbuf + 256;   float* sh2 = scbuf + 384;
    float* sc3 = scbuf + 512;   float* sh3 = scbuf + 640;

    size_t zlen = (size_t)((char*)(done + 8) - (char*)deg);
    (void)hipMemsetAsync(deg, 0, zlen, stream);                        // 1

    k_pre<<<PREP_BLKS + HIST_BLKS, 256, 0, stream>>>(W1, W2, W3, Wcat1, Wf2, Wf3,
                                                     dstp, deg, rank); // 2
    k_scanall<<<NBLK, 256, 0, stream>>>(deg, bsum, off);               // 3
    k_scatter<<<HIST_BLKS, 256, 0, stream>>>(srcp, dstp, off, rank, ssrc); // 4

    const dim3 MMG(MM_GRID, 2);
    const int AGB = N_NODES / 4;

    // layer 1
    k_mm1<F_IN, F_IN><<<MMG, 256, 0, stream>>>(x, Wcat1, b1, A, C);                 // 5
    k_agg<<<AGB, 256, 0, stream>>>(A, (const h2*)C, off, deg, ssrc, h);             // 6
    k_statsf<<<1000, 128, 0, stream>>>(h, sums0, g1, be1, sc1, sh1, done + 0);      // 7

    // layer 2 (MFMA)
    k_mmf<<<MMG, 256, 0, stream>>>(h, Wf2, b2, sc1, sh1, A, C);                     // 8
    k_agg<<<AGB, 256, 0, stream>>>(A, (const h2*)C, off, deg, ssrc, h);             // 9
    k_statsf<<<1000, 128, 0, stream>>>(h, sums1, g2, be2, sc2, sh2, done + 1);      // 10

    // layer 3 (MFMA)
    k_mmf<<<MMG, 256, 0, stream>>>(h, Wf3, b3, sc2, sh2, A, C);                     // 11
    k_agg<<<AGB, 256, 0, stream>>>(A, (const h2*)C, off, deg, ssrc, h);             // 12
    k_statsf<<<1000, 128, 0, stream>>>(h, sums2, g3, be3, sc3, sh3, done + 2);      // 13

    // fused pool + BN3 + linear + relu
    k_poolout<<<N_GRAPHS, 128, 0, stream>>>(h, sc3, sh3, Wl, bl, out);              // 14
}